// Round 2
// baseline (3784.332 us; speedup 1.0000x reference)
//
#include <hip/hip_runtime.h>

#define N_NODES 50000
#define N_EDGES 800000
#define N_GRAPHS 64
#define POOL_CHUNKS 8

// ---------------- degree / norm ----------------

__global__ void k_init_deg(float* deg) {
    int i = blockIdx.x * blockDim.x + threadIdx.x;
    if (i < N_NODES) deg[i] = 1.0f;   // self-loop contributes 1
}

__global__ void k_deg_scatter(const int* __restrict__ dst, float* deg) {
    int i = blockIdx.x * blockDim.x + threadIdx.x;
    if (i < N_EDGES) atomicAdd(&deg[dst[i]], 1.0f);
}

__global__ void k_rsqrt(float* deg) {
    int i = blockIdx.x * blockDim.x + threadIdx.x;
    if (i < N_NODES) deg[i] = rsqrtf(deg[i]);
}

// ---------------- dense node GEMM: out[n,:OUT_W] = relu?(h[n,:IN_W]) @ W ----------------
// NPB nodes per block; W column load reused across NPB rows.

template<int IN_W, int OUT_W, int NPB, bool RELU_IN>
__global__ void k_node_gemm(const float* __restrict__ h, const float* __restrict__ W,
                            float* __restrict__ out) {
    __shared__ float rows[NPB][IN_W];
    int n0 = blockIdx.x * NPB;
    int j = threadIdx.x;                         // blockDim.x == OUT_W
    for (int t = j; t < NPB * IN_W; t += OUT_W) {
        int m = t / IN_W, k = t - m * IN_W;
        int n = n0 + m;
        float v = (n < N_NODES) ? h[(size_t)n * IN_W + k] : 0.0f;
        rows[m][k] = RELU_IN ? fmaxf(v, 0.0f) : v;
    }
    __syncthreads();
    float acc[NPB];
#pragma unroll
    for (int m = 0; m < NPB; ++m) acc[m] = 0.0f;
#pragma unroll 4
    for (int k = 0; k < IN_W; ++k) {
        float wk = W[k * OUT_W + j];
#pragma unroll
        for (int m = 0; m < NPB; ++m) acc[m] += rows[m][k] * wk;
    }
#pragma unroll
    for (int m = 0; m < NPB; ++m) {
        int n = n0 + m;
        if (n < N_NODES) out[(size_t)n * OUT_W + j] = acc[m];
    }
}

// ---------------- agg init with bias ----------------

template<int W>
__global__ void k_fill_bias(float* __restrict__ agg, const float* __restrict__ b) {
    int t = blockIdx.x * blockDim.x + threadIdx.x;
    if (t < N_NODES * W) agg[t] = b[t & (W - 1)];
}

// ---------------- edge scatter: agg[dst] += h[src] * dinv[src]*dinv[dst] ----------------
// float4 gather; edges 0..N_EDGES-1 real, then N_NODES self-loops.

template<int W>
__global__ void k_scatter(const float* __restrict__ hw, const int* __restrict__ src,
                          const int* __restrict__ dst, const float* __restrict__ dinv,
                          float* agg) {
    const int TPE = W / 4;                 // threads per edge (float4 lanes)
    const int EPB = 256 / TPE;             // edges per block
    int e = blockIdx.x * EPB + threadIdx.x / TPE;
    int q = threadIdx.x % TPE;
    const int total = N_EDGES + N_NODES;
    if (e >= total) return;
    int s, d;
    if (e < N_EDGES) { s = src[e]; d = dst[e]; }
    else             { s = d = e - N_EDGES; }
    float w = dinv[s] * dinv[d];
    const float4* hv = (const float4*)(hw + (size_t)s * W);
    float4 v = hv[q];
    float* ap = agg + (size_t)d * W + q * 4;
    atomicAdd(ap + 0, v.x * w);
    atomicAdd(ap + 1, v.y * w);
    atomicAdd(ap + 2, v.z * w);
    atomicAdd(ap + 3, v.w * w);
}

// ---------------- pooling (batch is sorted -> binary-search graph ranges) ----------------

__device__ __forceinline__ int lower_bound_batch(const int* __restrict__ batch, int val) {
    int lo = 0, hi = N_NODES;
    while (lo < hi) {
        int mid = (lo + hi) >> 1;
        if (batch[mid] < val) lo = mid + 1; else hi = mid;
    }
    return lo;
}

__global__ void k_pool_zero(float* pooled, float* cnts) {
    int i = blockIdx.x * blockDim.x + threadIdx.x;
    if (i < N_GRAPHS * 128) pooled[i] = 0.0f;
    if (i < N_GRAPHS) cnts[i] = 0.0f;
}

// grid = N_GRAPHS * POOL_CHUNKS, block = 128. ReLU folded into the read.
__global__ void k_pool(const float* __restrict__ h, const int* __restrict__ batch,
                       float* pooled, float* cnts) {
    int g = blockIdx.x / POOL_CHUNKS;
    int c = blockIdx.x - g * POOL_CHUNKS;
    int j = threadIdx.x;
    int lo = lower_bound_batch(batch, g);
    int hi = lower_bound_batch(batch, g + 1);
    int len = hi - lo;
    if (c == 0 && j == 0) cnts[g] = (float)len;
    int s = lo + (int)(((long long)len * c) / POOL_CHUNKS);
    int e = lo + (int)(((long long)len * (c + 1)) / POOL_CHUNKS);
    float acc = 0.0f;
    for (int n = s; n < e; ++n) acc += fmaxf(h[(size_t)n * 128 + j], 0.0f);
    atomicAdd(&pooled[g * 128 + j], acc);
}

// ---------------- final FC head ----------------

__global__ void k_fc(const float* __restrict__ pooled, const float* __restrict__ cnts,
                     const float* __restrict__ Wf1, const float* __restrict__ bf1,
                     const float* __restrict__ Wf2, const float* __restrict__ bf2,
                     float* __restrict__ out) {
    __shared__ float sp[128];
    __shared__ float sh1[64];
    int g = blockIdx.x;
    int t = threadIdx.x;             // 128
    float inv = 1.0f / fmaxf(cnts[g], 1.0f);
    sp[t] = pooled[g * 128 + t] * inv;
    __syncthreads();
    if (t < 64) {
        float acc = bf1[t];
#pragma unroll 8
        for (int k = 0; k < 128; ++k) acc += sp[k] * Wf1[k * 64 + t];
        sh1[t] = fmaxf(acc, 0.0f);
    }
    __syncthreads();
    if (t < 10) {
        float acc = bf2[t];
#pragma unroll 8
        for (int k = 0; k < 64; ++k) acc += sh1[k] * Wf2[k * 10 + t];
        out[g * 10 + t] = acc;
    }
}

extern "C" void kernel_launch(void* const* d_in, const int* in_sizes, int n_in,
                              void* d_out, int out_size, void* d_ws, size_t ws_size,
                              hipStream_t stream) {
    const float* x     = (const float*)d_in[0];
    const int*   ei    = (const int*)d_in[1];
    const int*   batch = (const int*)d_in[2];
    const float* W1  = (const float*)d_in[3];
    const float* b1  = (const float*)d_in[4];
    const float* W2  = (const float*)d_in[5];
    const float* b2  = (const float*)d_in[6];
    const float* W3  = (const float*)d_in[7];
    const float* b3  = (const float*)d_in[8];
    const float* Wf1 = (const float*)d_in[9];
    const float* bf1 = (const float*)d_in[10];
    const float* Wf2 = (const float*)d_in[11];
    const float* bf2 = (const float*)d_in[12];
    float* out = (float*)d_out;

    const int* src = ei;              // edge_index[0]
    const int* dst = ei + N_EDGES;    // edge_index[1]

    // workspace layout (floats)
    float* deg    = (float*)d_ws;                 // N
    float* bufA   = deg + N_NODES;                // N*128
    float* bufB   = bufA + N_NODES * 128;         // N*128
    float* pooled = bufB + N_NODES * 128;         // G*128
    float* cnts   = pooled + N_GRAPHS * 128;      // G

    const int TB = 256;
    const int totE = N_EDGES + N_NODES;

    // degree + norm
    k_init_deg<<<(N_NODES + TB - 1) / TB, TB, 0, stream>>>(deg);
    k_deg_scatter<<<(N_EDGES + TB - 1) / TB, TB, 0, stream>>>(dst, deg);
    k_rsqrt<<<(N_NODES + TB - 1) / TB, TB, 0, stream>>>(deg);

    // ---- layer 1: 3 -> 64 ----
    k_node_gemm<3, 64, 4, false><<<(N_NODES + 3) / 4, 64, 0, stream>>>(x, W1, bufA);
    k_fill_bias<64><<<(N_NODES * 64 + TB - 1) / TB, TB, 0, stream>>>(bufB, b1);
    {   const int EPB = 256 / (64 / 4);
        k_scatter<64><<<(totE + EPB - 1) / EPB, TB, 0, stream>>>(bufA, src, dst, deg, bufB); }

    // ---- layer 2: 64 -> 128 ----  (relu of layer-1 output folded into gemm read)
    k_node_gemm<64, 128, 4, true><<<(N_NODES + 3) / 4, 128, 0, stream>>>(bufB, W2, bufA);
    k_fill_bias<128><<<(N_NODES * 128 + TB - 1) / TB, TB, 0, stream>>>(bufB, b2);
    {   const int EPB = 256 / (128 / 4);
        k_scatter<128><<<(totE + EPB - 1) / EPB, TB, 0, stream>>>(bufA, src, dst, deg, bufB); }

    // ---- layer 3: 128 -> 128 ----
    k_node_gemm<128, 128, 4, true><<<(N_NODES + 3) / 4, 128, 0, stream>>>(bufB, W3, bufA);
    k_fill_bias<128><<<(N_NODES * 128 + TB - 1) / TB, TB, 0, stream>>>(bufB, b3);
    {   const int EPB = 256 / (128 / 4);
        k_scatter<128><<<(totE + EPB - 1) / EPB, TB, 0, stream>>>(bufA, src, dst, deg, bufB); }

    // ---- global mean pool (relu folded) + FC head ----
    k_pool_zero<<<(N_GRAPHS * 128 + TB - 1) / TB, TB, 0, stream>>>(pooled, cnts);
    k_pool<<<N_GRAPHS * POOL_CHUNKS, 128, 0, stream>>>(bufB, batch, pooled, cnts);
    k_fc<<<N_GRAPHS, 128, 0, stream>>>(pooled, cnts, Wf1, bf1, Wf2, bf2, out);
}

// Round 3
// 2834.761 us; speedup vs baseline: 1.3350x; 1.3350x over previous
//
#include <hip/hip_runtime.h>

#define N_NODES 50000
#define N_EDGES 800000
#define N_GRAPHS 64
#define POOL_CHUNKS 8
#define TOT_E (N_EDGES + N_NODES)
#define SCAN_B 256
#define SCAN_NBLK ((N_NODES + SCAN_B - 1) / SCAN_B)   // 196

// ================= CSR build =================

__global__ void k_init_counts(int* counts) {
    int i = blockIdx.x * blockDim.x + threadIdx.x;
    if (i < N_NODES) counts[i] = 1;            // self-loop slot
}

__global__ void k_hist(const int* __restrict__ dst, int* counts) {
    int i = blockIdx.x * blockDim.x + threadIdx.x;
    if (i < N_EDGES) atomicAdd(&counts[dst[i]], 1);
}

// per-block exclusive scan of counts -> row_ptr, block totals -> blksum
__global__ void k_scan1(const int* __restrict__ counts, int* row_ptr, int* blksum) {
    __shared__ int s[SCAN_B];
    int i = blockIdx.x * SCAN_B + threadIdx.x;
    int c = (i < N_NODES) ? counts[i] : 0;
    s[threadIdx.x] = c;
    __syncthreads();
    for (int off = 1; off < SCAN_B; off <<= 1) {
        int v = (threadIdx.x >= off) ? s[threadIdx.x - off] : 0;
        __syncthreads();
        s[threadIdx.x] += v;
        __syncthreads();
    }
    if (i < N_NODES) row_ptr[i] = s[threadIdx.x] - c;   // exclusive
    if (threadIdx.x == SCAN_B - 1) blksum[blockIdx.x] = s[SCAN_B - 1];
}

// single block: exclusive scan of blksum in place
__global__ void k_scan2(int* blksum) {
    __shared__ int s[SCAN_B];
    int t = threadIdx.x;
    int c = (t < SCAN_NBLK) ? blksum[t] : 0;
    s[t] = c;
    __syncthreads();
    for (int off = 1; off < SCAN_B; off <<= 1) {
        int v = (t >= off) ? s[t - off] : 0;
        __syncthreads();
        s[t] += v;
        __syncthreads();
    }
    if (t < SCAN_NBLK) blksum[t] = s[t] - c;            // exclusive
}

// finalize row_ptr, init cursor, compute dinv
__global__ void k_scan3(int* row_ptr, const int* __restrict__ blksum,
                        int* cursor, const int* __restrict__ counts, float* dinv) {
    int i = blockIdx.x * blockDim.x + threadIdx.x;
    if (i < N_NODES) {
        int v = row_ptr[i] + blksum[i / SCAN_B];
        row_ptr[i] = v;
        cursor[i] = v;
        dinv[i] = rsqrtf((float)counts[i]);
    }
    if (i == 0) row_ptr[N_NODES] = TOT_E;
}

// fill csr_src: real edges then self-loops
__global__ void k_fill(const int* __restrict__ src, const int* __restrict__ dst,
                       int* cursor, int* csr_src) {
    int e = blockIdx.x * blockDim.x + threadIdx.x;
    if (e >= TOT_E) return;
    int s, d;
    if (e < N_EDGES) { s = src[e]; d = dst[e]; }
    else             { s = d = e - N_EDGES; }
    int pos = atomicAdd(&cursor[d], 1);
    csr_src[pos] = s;
}

// ================= dense node GEMM: out[n,:OUT_W] = relu?(h[n,:IN_W]) @ W =========

template<int IN_W, int OUT_W, int NPB, bool RELU_IN>
__global__ void k_node_gemm(const float* __restrict__ h, const float* __restrict__ W,
                            float* __restrict__ out) {
    __shared__ __align__(16) float rows[NPB][IN_W];
    int n0 = blockIdx.x * NPB;
    int j = threadIdx.x;                         // blockDim.x == OUT_W
    for (int t = j; t < NPB * IN_W; t += OUT_W) {
        int m = t / IN_W, k = t - m * IN_W;
        int n = n0 + m;
        float v = (n < N_NODES) ? h[(size_t)n * IN_W + k] : 0.0f;
        rows[m][k] = RELU_IN ? fmaxf(v, 0.0f) : v;
    }
    __syncthreads();
    float acc[NPB];
#pragma unroll
    for (int m = 0; m < NPB; ++m) acc[m] = 0.0f;

    if (IN_W % 4 == 0) {
        for (int k = 0; k < IN_W; k += 4) {
            float4 r[NPB];
#pragma unroll
            for (int m = 0; m < NPB; ++m) r[m] = *(const float4*)&rows[m][k];
#pragma unroll
            for (int kk = 0; kk < 4; ++kk) {
                float wk = W[(k + kk) * OUT_W + j];
#pragma unroll
                for (int m = 0; m < NPB; ++m)
                    acc[m] += ((const float*)&r[m])[kk] * wk;
            }
        }
    } else {
#pragma unroll
        for (int k = 0; k < IN_W; ++k) {
            float wk = W[k * OUT_W + j];
#pragma unroll
            for (int m = 0; m < NPB; ++m) acc[m] += rows[m][k] * wk;
        }
    }
#pragma unroll
    for (int m = 0; m < NPB; ++m) {
        int n = n0 + m;
        if (n < N_NODES) out[(size_t)n * OUT_W + j] = acc[m];
    }
}

// ================= CSR gather aggregation (no atomics), bias folded ==============

// width 64: one wave per node, lane = feature
__global__ void k_agg64(const float* __restrict__ hw, const int* __restrict__ row_ptr,
                        const int* __restrict__ csr_src, const float* __restrict__ dinv,
                        const float* __restrict__ b, float* __restrict__ out) {
    int wv = (blockIdx.x * blockDim.x + threadIdx.x) >> 6;
    int lane = threadIdx.x & 63;
    if (wv >= N_NODES) return;
    int lo = row_ptr[wv], hi = row_ptr[wv + 1];
    float din = dinv[wv];
    float acc = b[lane];
    for (int i = lo; i < hi; ++i) {
        int s = csr_src[i];
        float w = dinv[s] * din;
        acc += hw[(size_t)s * 64 + lane] * w;
    }
    out[(size_t)wv * 64 + lane] = acc;
}

// width 128: one wave per node, lane = float2 feature pair
__global__ void k_agg128(const float* __restrict__ hw, const int* __restrict__ row_ptr,
                         const int* __restrict__ csr_src, const float* __restrict__ dinv,
                         const float* __restrict__ b, float* __restrict__ out) {
    int wv = (blockIdx.x * blockDim.x + threadIdx.x) >> 6;
    int lane = threadIdx.x & 63;
    if (wv >= N_NODES) return;
    int lo = row_ptr[wv], hi = row_ptr[wv + 1];
    float din = dinv[wv];
    float2 acc = ((const float2*)b)[lane];
    for (int i = lo; i < hi; ++i) {
        int s = csr_src[i];
        float w = dinv[s] * din;
        float2 v = *(const float2*)(hw + (size_t)s * 128 + 2 * lane);
        acc.x += v.x * w;
        acc.y += v.y * w;
    }
    *(float2*)(out + (size_t)wv * 128 + 2 * lane) = acc;
}

// ================= pooling (batch sorted -> binary search ranges) ================

__device__ __forceinline__ int lower_bound_batch(const int* __restrict__ batch, int val) {
    int lo = 0, hi = N_NODES;
    while (lo < hi) {
        int mid = (lo + hi) >> 1;
        if (batch[mid] < val) lo = mid + 1; else hi = mid;
    }
    return lo;
}

__global__ void k_pool_zero(float* pooled, float* cnts) {
    int i = blockIdx.x * blockDim.x + threadIdx.x;
    if (i < N_GRAPHS * 128) pooled[i] = 0.0f;
    if (i < N_GRAPHS) cnts[i] = 0.0f;
}

__global__ void k_pool(const float* __restrict__ h, const int* __restrict__ batch,
                       float* pooled, float* cnts) {
    int g = blockIdx.x / POOL_CHUNKS;
    int c = blockIdx.x - g * POOL_CHUNKS;
    int j = threadIdx.x;
    int lo = lower_bound_batch(batch, g);
    int hi = lower_bound_batch(batch, g + 1);
    int len = hi - lo;
    if (c == 0 && j == 0) cnts[g] = (float)len;
    int s = lo + (int)(((long long)len * c) / POOL_CHUNKS);
    int e = lo + (int)(((long long)len * (c + 1)) / POOL_CHUNKS);
    float acc = 0.0f;
    for (int n = s; n < e; ++n) acc += fmaxf(h[(size_t)n * 128 + j], 0.0f);
    atomicAdd(&pooled[g * 128 + j], acc);
}

// ================= final FC head =================

__global__ void k_fc(const float* __restrict__ pooled, const float* __restrict__ cnts,
                     const float* __restrict__ Wf1, const float* __restrict__ bf1,
                     const float* __restrict__ Wf2, const float* __restrict__ bf2,
                     float* __restrict__ out) {
    __shared__ float sp[128];
    __shared__ float sh1[64];
    int g = blockIdx.x;
    int t = threadIdx.x;             // 128
    float inv = 1.0f / fmaxf(cnts[g], 1.0f);
    sp[t] = pooled[g * 128 + t] * inv;
    __syncthreads();
    if (t < 64) {
        float acc = bf1[t];
#pragma unroll 8
        for (int k = 0; k < 128; ++k) acc += sp[k] * Wf1[k * 64 + t];
        sh1[t] = fmaxf(acc, 0.0f);
    }
    __syncthreads();
    if (t < 10) {
        float acc = bf2[t];
#pragma unroll 8
        for (int k = 0; k < 64; ++k) acc += sh1[k] * Wf2[k * 10 + t];
        out[g * 10 + t] = acc;
    }
}

extern "C" void kernel_launch(void* const* d_in, const int* in_sizes, int n_in,
                              void* d_out, int out_size, void* d_ws, size_t ws_size,
                              hipStream_t stream) {
    const float* x     = (const float*)d_in[0];
    const int*   ei    = (const int*)d_in[1];
    const int*   batch = (const int*)d_in[2];
    const float* W1  = (const float*)d_in[3];
    const float* b1  = (const float*)d_in[4];
    const float* W2  = (const float*)d_in[5];
    const float* b2  = (const float*)d_in[6];
    const float* W3  = (const float*)d_in[7];
    const float* b3  = (const float*)d_in[8];
    const float* Wf1 = (const float*)d_in[9];
    const float* bf1 = (const float*)d_in[10];
    const float* Wf2 = (const float*)d_in[11];
    const float* bf2 = (const float*)d_in[12];
    float* out = (float*)d_out;

    const int* src = ei;              // edge_index[0]
    const int* dst = ei + N_EDGES;    // edge_index[1]

    // workspace layout
    float* dinv   = (float*)d_ws;                      // N
    int*   counts = (int*)(dinv + N_NODES);            // N
    int*   row_ptr= counts + N_NODES;                  // N+1
    int*   blksum = row_ptr + N_NODES + 1;             // 256
    int*   cursor = blksum + 256;                      // N
    int*   csr_src= cursor + N_NODES;                  // TOT_E
    size_t ofs = (size_t)(csr_src + TOT_E) - (size_t)d_ws;
    ofs = (ofs + 15) & ~(size_t)15;                    // 16B align
    float* bufA   = (float*)((char*)d_ws + ofs);       // N*128
    float* bufB   = bufA + (size_t)N_NODES * 128;      // N*128
    float* pooled = bufB + (size_t)N_NODES * 128;      // G*128
    float* cnts   = pooled + N_GRAPHS * 128;           // G

    const int TB = 256;

    // ---- CSR build + norm ----
    k_init_counts<<<(N_NODES + TB - 1) / TB, TB, 0, stream>>>(counts);
    k_hist<<<(N_EDGES + TB - 1) / TB, TB, 0, stream>>>(dst, counts);
    k_scan1<<<SCAN_NBLK, SCAN_B, 0, stream>>>(counts, row_ptr, blksum);
    k_scan2<<<1, SCAN_B, 0, stream>>>(blksum);
    k_scan3<<<(N_NODES + TB - 1) / TB, TB, 0, stream>>>(row_ptr, blksum, cursor, counts, dinv);
    k_fill<<<(TOT_E + TB - 1) / TB, TB, 0, stream>>>(src, dst, cursor, csr_src);

    // ---- layer 1: 3 -> 64 ----
    k_node_gemm<3, 64, 4, false><<<(N_NODES + 3) / 4, 64, 0, stream>>>(x, W1, bufA);
    k_agg64<<<(N_NODES * 64 + TB - 1) / TB, TB, 0, stream>>>(bufA, row_ptr, csr_src, dinv, b1, bufB);

    // ---- layer 2: 64 -> 128 ---- (relu folded into gemm read)
    k_node_gemm<64, 128, 4, true><<<(N_NODES + 3) / 4, 128, 0, stream>>>(bufB, W2, bufA);
    k_agg128<<<(N_NODES * 64 + TB - 1) / TB, TB, 0, stream>>>(bufA, row_ptr, csr_src, dinv, b2, bufB);

    // ---- layer 3: 128 -> 128 ----
    k_node_gemm<128, 128, 4, true><<<(N_NODES + 3) / 4, 128, 0, stream>>>(bufB, W3, bufA);
    k_agg128<<<(N_NODES * 64 + TB - 1) / TB, TB, 0, stream>>>(bufA, row_ptr, csr_src, dinv, b3, bufB);

    // ---- global mean pool (relu folded) + FC head ----
    k_pool_zero<<<(N_GRAPHS * 128 + TB - 1) / TB, TB, 0, stream>>>(pooled, cnts);
    k_pool<<<N_GRAPHS * POOL_CHUNKS, 128, 0, stream>>>(bufB, batch, pooled, cnts);
    k_fc<<<N_GRAPHS, 128, 0, stream>>>(pooled, cnts, Wf1, bf1, Wf2, bf2, out);
}

// Round 4
// 546.352 us; speedup vs baseline: 6.9265x; 5.1885x over previous
//
#include <hip/hip_runtime.h>

#define N_NODES 50000
#define N_EDGES 800000
#define N_GRAPHS 64
#define POOL_CHUNKS 8
#define TOT_E (N_EDGES + N_NODES)
#define SCAN_B 256
#define SCAN_NBLK ((N_NODES + SCAN_B - 1) / SCAN_B)   // 196

// ================= CSR build =================

__global__ void k_init_counts(int* counts) {
    int i = blockIdx.x * blockDim.x + threadIdx.x;
    if (i < N_NODES) counts[i] = 1;            // self-loop slot
}

__global__ void k_hist(const int* __restrict__ dst, int* counts) {
    int i = blockIdx.x * blockDim.x + threadIdx.x;
    if (i < N_EDGES) atomicAdd(&counts[dst[i]], 1);
}

__global__ void k_scan1(const int* __restrict__ counts, int* row_ptr, int* blksum) {
    __shared__ int s[SCAN_B];
    int i = blockIdx.x * SCAN_B + threadIdx.x;
    int c = (i < N_NODES) ? counts[i] : 0;
    s[threadIdx.x] = c;
    __syncthreads();
    for (int off = 1; off < SCAN_B; off <<= 1) {
        int v = (threadIdx.x >= off) ? s[threadIdx.x - off] : 0;
        __syncthreads();
        s[threadIdx.x] += v;
        __syncthreads();
    }
    if (i < N_NODES) row_ptr[i] = s[threadIdx.x] - c;   // exclusive
    if (threadIdx.x == SCAN_B - 1) blksum[blockIdx.x] = s[SCAN_B - 1];
}

__global__ void k_scan2(int* blksum) {
    __shared__ int s[SCAN_B];
    int t = threadIdx.x;
    int c = (t < SCAN_NBLK) ? blksum[t] : 0;
    s[t] = c;
    __syncthreads();
    for (int off = 1; off < SCAN_B; off <<= 1) {
        int v = (t >= off) ? s[t - off] : 0;
        __syncthreads();
        s[t] += v;
        __syncthreads();
    }
    if (t < SCAN_NBLK) blksum[t] = s[t] - c;            // exclusive
}

__global__ void k_scan3(int* row_ptr, const int* __restrict__ blksum,
                        int* cursor, const int* __restrict__ counts, float* dinv) {
    int i = blockIdx.x * blockDim.x + threadIdx.x;
    if (i < N_NODES) {
        int v = row_ptr[i] + blksum[i / SCAN_B];
        row_ptr[i] = v;
        cursor[i] = v;
        dinv[i] = rsqrtf((float)counts[i]);
    }
    if (i == 0) row_ptr[N_NODES] = TOT_E;
}

__global__ void k_fill(const int* __restrict__ src, const int* __restrict__ dst,
                       int* cursor, int* csr_src) {
    int e = blockIdx.x * blockDim.x + threadIdx.x;
    if (e >= TOT_E) return;
    int s, d;
    if (e < N_EDGES) { s = src[e]; d = dst[e]; }
    else             { s = d = e - N_EDGES; }
    int pos = atomicAdd(&cursor[d], 1);
    csr_src[pos] = s;
}

// ================= layer-1 GEMM (K=3): simple scalar, was never hot ==============

template<int IN_W, int OUT_W, int NPB, bool RELU_IN>
__global__ void k_node_gemm(const float* __restrict__ h, const float* __restrict__ W,
                            float* __restrict__ out) {
    __shared__ float rows[NPB][IN_W];
    int n0 = blockIdx.x * NPB;
    int j = threadIdx.x;                         // blockDim.x == OUT_W
    for (int t = j; t < NPB * IN_W; t += OUT_W) {
        int m = t / IN_W, k = t - m * IN_W;
        int n = n0 + m;
        float v = (n < N_NODES) ? h[(size_t)n * IN_W + k] : 0.0f;
        rows[m][k] = RELU_IN ? fmaxf(v, 0.0f) : v;
    }
    __syncthreads();
    float acc[NPB];
#pragma unroll
    for (int m = 0; m < NPB; ++m) acc[m] = 0.0f;
#pragma unroll
    for (int k = 0; k < IN_W; ++k) {
        float wk = W[k * OUT_W + j];
#pragma unroll
        for (int m = 0; m < NPB; ++m) acc[m] += rows[m][k] * wk;
    }
#pragma unroll
    for (int m = 0; m < NPB; ++m) {
        int n = n0 + m;
        if (n < N_NODES) out[(size_t)n * OUT_W + j] = acc[m];
    }
}

// ================= tiled GEMM: C[M x 128] = relu?(A[M x K]) @ W[K x 128] =========
// 256 threads, 64 rows/block, K-chunk 32. No address-taken locals (scratch-free).

#define GM 64
#define GKC 32

template<int K, bool RELU_IN>
__global__ __launch_bounds__(256) void k_gemm128(const float* __restrict__ A,
                                                 const float* __restrict__ W,
                                                 float* __restrict__ C) {
    __shared__ __align__(16) float sA[GM][GKC];    // 8 KB (unpadded: staging is tid*8 contiguous)
    __shared__ __align__(16) float sW[GKC][128];   // 16 KB
    int n0 = blockIdx.x * GM;
    int tid = threadIdx.x;
    int tj = tid & 31;          // col group: cols 4*tj .. 4*tj+3
    int tn = tid >> 5;          // row group: rows 8*tn .. 8*tn+7

    float acc[8][4];
#pragma unroll
    for (int m = 0; m < 8; ++m)
#pragma unroll
        for (int c = 0; c < 4; ++c) acc[m][c] = 0.0f;

    for (int k0 = 0; k0 < K; k0 += GKC) {
        // ---- stage A tile: 64 x 32 (thread -> 8 contiguous floats = LDS offset tid*8) ----
        {
            int r  = tid >> 2;                 // 0..63
            int kq = (tid & 3) * 8;            // 0,8,16,24
            int n  = n0 + r;
            float4 v0 = make_float4(0.f, 0.f, 0.f, 0.f);
            float4 v1 = make_float4(0.f, 0.f, 0.f, 0.f);
            if (n < N_NODES) {
                const float* ap = A + (size_t)n * K + k0 + kq;
                v0 = *(const float4*)ap;
                v1 = *(const float4*)(ap + 4);
            }
            if (RELU_IN) {
                v0.x = fmaxf(v0.x, 0.f); v0.y = fmaxf(v0.y, 0.f);
                v0.z = fmaxf(v0.z, 0.f); v0.w = fmaxf(v0.w, 0.f);
                v1.x = fmaxf(v1.x, 0.f); v1.y = fmaxf(v1.y, 0.f);
                v1.z = fmaxf(v1.z, 0.f); v1.w = fmaxf(v1.w, 0.f);
            }
            float* sp = &sA[r][kq];
            *(float4*)sp = v0;
            *(float4*)(sp + 4) = v1;
        }
        // ---- stage W tile: 32 x 128 contiguous (coalesced float4) ----
        {
            const float* Wc = W + k0 * 128;
            float* sWf = &sW[0][0];
#pragma unroll
            for (int i = 0; i < 4; ++i) {
                int e = (tid + i * 256) * 4;
                *(float4*)(sWf + e) = *(const float4*)(Wc + e);
            }
        }
        __syncthreads();
#pragma unroll
        for (int kk = 0; kk < GKC; ++kk) {
            float4 w = *(const float4*)&sW[kk][tj * 4];
#pragma unroll
            for (int m = 0; m < 8; ++m) {
                float a = sA[tn * 8 + m][kk];
                acc[m][0] += a * w.x;
                acc[m][1] += a * w.y;
                acc[m][2] += a * w.z;
                acc[m][3] += a * w.w;
            }
        }
        __syncthreads();
    }
#pragma unroll
    for (int m = 0; m < 8; ++m) {
        int n = n0 + tn * 8 + m;
        if (n < N_NODES) {
            float4 o = make_float4(acc[m][0], acc[m][1], acc[m][2], acc[m][3]);
            *(float4*)(C + (size_t)n * 128 + tj * 4) = o;
        }
    }
}

// ================= CSR gather aggregation (no atomics), bias folded ==============

__global__ void k_agg64(const float* __restrict__ hw, const int* __restrict__ row_ptr,
                        const int* __restrict__ csr_src, const float* __restrict__ dinv,
                        const float* __restrict__ b, float* __restrict__ out) {
    int wv = (blockIdx.x * blockDim.x + threadIdx.x) >> 6;
    int lane = threadIdx.x & 63;
    if (wv >= N_NODES) return;
    int lo = row_ptr[wv], hi = row_ptr[wv + 1];
    float din = dinv[wv];
    float acc = b[lane];
    for (int i = lo; i < hi; ++i) {
        int s = csr_src[i];
        float w = dinv[s] * din;
        acc += hw[(size_t)s * 64 + lane] * w;
    }
    out[(size_t)wv * 64 + lane] = acc;
}

__global__ void k_agg128(const float* __restrict__ hw, const int* __restrict__ row_ptr,
                         const int* __restrict__ csr_src, const float* __restrict__ dinv,
                         const float* __restrict__ b, float* __restrict__ out) {
    int wv = (blockIdx.x * blockDim.x + threadIdx.x) >> 6;
    int lane = threadIdx.x & 63;
    if (wv >= N_NODES) return;
    int lo = row_ptr[wv], hi = row_ptr[wv + 1];
    float din = dinv[wv];
    float2 acc = ((const float2*)b)[lane];
    for (int i = lo; i < hi; ++i) {
        int s = csr_src[i];
        float w = dinv[s] * din;
        float2 v = *(const float2*)(hw + (size_t)s * 128 + 2 * lane);
        acc.x += v.x * w;
        acc.y += v.y * w;
    }
    *(float2*)(out + (size_t)wv * 128 + 2 * lane) = acc;
}

// ================= pooling (batch sorted -> binary search ranges) ================

__device__ __forceinline__ int lower_bound_batch(const int* __restrict__ batch, int val) {
    int lo = 0, hi = N_NODES;
    while (lo < hi) {
        int mid = (lo + hi) >> 1;
        if (batch[mid] < val) lo = mid + 1; else hi = mid;
    }
    return lo;
}

__global__ void k_pool_zero(float* pooled, float* cnts) {
    int i = blockIdx.x * blockDim.x + threadIdx.x;
    if (i < N_GRAPHS * 128) pooled[i] = 0.0f;
    if (i < N_GRAPHS) cnts[i] = 0.0f;
}

__global__ void k_pool(const float* __restrict__ h, const int* __restrict__ batch,
                       float* pooled, float* cnts) {
    int g = blockIdx.x / POOL_CHUNKS;
    int c = blockIdx.x - g * POOL_CHUNKS;
    int j = threadIdx.x;
    int lo = lower_bound_batch(batch, g);
    int hi = lower_bound_batch(batch, g + 1);
    int len = hi - lo;
    if (c == 0 && j == 0) cnts[g] = (float)len;
    int s = lo + (int)(((long long)len * c) / POOL_CHUNKS);
    int e = lo + (int)(((long long)len * (c + 1)) / POOL_CHUNKS);
    float acc = 0.0f;
    for (int n = s; n < e; ++n) acc += fmaxf(h[(size_t)n * 128 + j], 0.0f);
    atomicAdd(&pooled[g * 128 + j], acc);
}

// ================= final FC head =================

__global__ void k_fc(const float* __restrict__ pooled, const float* __restrict__ cnts,
                     const float* __restrict__ Wf1, const float* __restrict__ bf1,
                     const float* __restrict__ Wf2, const float* __restrict__ bf2,
                     float* __restrict__ out) {
    __shared__ float sp[128];
    __shared__ float sh1[64];
    int g = blockIdx.x;
    int t = threadIdx.x;             // 128
    float inv = 1.0f / fmaxf(cnts[g], 1.0f);
    sp[t] = pooled[g * 128 + t] * inv;
    __syncthreads();
    if (t < 64) {
        float acc = bf1[t];
#pragma unroll 8
        for (int k = 0; k < 128; ++k) acc += sp[k] * Wf1[k * 64 + t];
        sh1[t] = fmaxf(acc, 0.0f);
    }
    __syncthreads();
    if (t < 10) {
        float acc = bf2[t];
#pragma unroll 8
        for (int k = 0; k < 64; ++k) acc += sh1[k] * Wf2[k * 10 + t];
        out[g * 10 + t] = acc;
    }
}

extern "C" void kernel_launch(void* const* d_in, const int* in_sizes, int n_in,
                              void* d_out, int out_size, void* d_ws, size_t ws_size,
                              hipStream_t stream) {
    const float* x     = (const float*)d_in[0];
    const int*   ei    = (const int*)d_in[1];
    const int*   batch = (const int*)d_in[2];
    const float* W1  = (const float*)d_in[3];
    const float* b1  = (const float*)d_in[4];
    const float* W2  = (const float*)d_in[5];
    const float* b2  = (const float*)d_in[6];
    const float* W3  = (const float*)d_in[7];
    const float* b3  = (const float*)d_in[8];
    const float* Wf1 = (const float*)d_in[9];
    const float* bf1 = (const float*)d_in[10];
    const float* Wf2 = (const float*)d_in[11];
    const float* bf2 = (const float*)d_in[12];
    float* out = (float*)d_out;

    const int* src = ei;              // edge_index[0]
    const int* dst = ei + N_EDGES;    // edge_index[1]

    // workspace layout
    float* dinv   = (float*)d_ws;                      // N
    int*   counts = (int*)(dinv + N_NODES);            // N
    int*   row_ptr= counts + N_NODES;                  // N+1
    int*   blksum = row_ptr + N_NODES + 1;             // 256
    int*   cursor = blksum + 256;                      // N
    int*   csr_src= cursor + N_NODES;                  // TOT_E
    size_t ofs = (size_t)(csr_src + TOT_E) - (size_t)d_ws;
    ofs = (ofs + 15) & ~(size_t)15;                    // 16B align
    float* bufA   = (float*)((char*)d_ws + ofs);       // N*128
    float* bufB   = bufA + (size_t)N_NODES * 128;      // N*128
    float* pooled = bufB + (size_t)N_NODES * 128;      // G*128
    float* cnts   = pooled + N_GRAPHS * 128;           // G

    const int TB = 256;

    // ---- CSR build + norm ----
    k_init_counts<<<(N_NODES + TB - 1) / TB, TB, 0, stream>>>(counts);
    k_hist<<<(N_EDGES + TB - 1) / TB, TB, 0, stream>>>(dst, counts);
    k_scan1<<<SCAN_NBLK, SCAN_B, 0, stream>>>(counts, row_ptr, blksum);
    k_scan2<<<1, SCAN_B, 0, stream>>>(blksum);
    k_scan3<<<(N_NODES + TB - 1) / TB, TB, 0, stream>>>(row_ptr, blksum, cursor, counts, dinv);
    k_fill<<<(TOT_E + TB - 1) / TB, TB, 0, stream>>>(src, dst, cursor, csr_src);

    // ---- layer 1: 3 -> 64 ----
    k_node_gemm<3, 64, 4, false><<<(N_NODES + 3) / 4, 64, 0, stream>>>(x, W1, bufA);
    k_agg64<<<(N_NODES * 64 + TB - 1) / TB, TB, 0, stream>>>(bufA, row_ptr, csr_src, dinv, b1, bufB);

    // ---- layer 2: 64 -> 128 ---- (relu folded into gemm A-load)
    k_gemm128<64, true><<<(N_NODES + GM - 1) / GM, 256, 0, stream>>>(bufB, W2, bufA);
    k_agg128<<<(N_NODES * 64 + TB - 1) / TB, TB, 0, stream>>>(bufA, row_ptr, csr_src, dinv, b2, bufB);

    // ---- layer 3: 128 -> 128 ----
    k_gemm128<128, true><<<(N_NODES + GM - 1) / GM, 256, 0, stream>>>(bufB, W3, bufA);
    k_agg128<<<(N_NODES * 64 + TB - 1) / TB, TB, 0, stream>>>(bufA, row_ptr, csr_src, dinv, b3, bufB);

    // ---- global mean pool (relu folded) + FC head ----
    k_pool_zero<<<(N_GRAPHS * 128 + TB - 1) / TB, TB, 0, stream>>>(pooled, cnts);
    k_pool<<<N_GRAPHS * POOL_CHUNKS, 128, 0, stream>>>(bufB, batch, pooled, cnts);
    k_fc<<<N_GRAPHS, 128, 0, stream>>>(pooled, cnts, Wf1, bf1, Wf2, bf2, out);
}

// Round 5
// 431.251 us; speedup vs baseline: 8.7752x; 1.2669x over previous
//
#include <hip/hip_runtime.h>

#define N_NODES 50000
#define N_EDGES 800000
#define N_GRAPHS 64
#define POOL_CHUNKS 8
#define TOT_E (N_EDGES + N_NODES)
#define SCAN_B 256
#define SCAN_NBLK ((N_NODES + SCAN_B - 1) / SCAN_B)   // 196

// ================= CSR build =================

__global__ void k_init_counts(int* counts) {
    int i = blockIdx.x * blockDim.x + threadIdx.x;
    if (i < N_NODES) counts[i] = 1;            // self-loop slot
}

__global__ void k_hist(const int* __restrict__ dst, int* counts) {
    int i = blockIdx.x * blockDim.x + threadIdx.x;
    if (i < N_EDGES) atomicAdd(&counts[dst[i]], 1);
}

__global__ void k_scan1(const int* __restrict__ counts, int* row_ptr, int* blksum) {
    __shared__ int s[SCAN_B];
    int i = blockIdx.x * SCAN_B + threadIdx.x;
    int c = (i < N_NODES) ? counts[i] : 0;
    s[threadIdx.x] = c;
    __syncthreads();
    for (int off = 1; off < SCAN_B; off <<= 1) {
        int v = (threadIdx.x >= off) ? s[threadIdx.x - off] : 0;
        __syncthreads();
        s[threadIdx.x] += v;
        __syncthreads();
    }
    if (i < N_NODES) row_ptr[i] = s[threadIdx.x] - c;   // exclusive
    if (threadIdx.x == SCAN_B - 1) blksum[blockIdx.x] = s[SCAN_B - 1];
}

__global__ void k_scan2(int* blksum) {
    __shared__ int s[SCAN_B];
    int t = threadIdx.x;
    int c = (t < SCAN_NBLK) ? blksum[t] : 0;
    s[t] = c;
    __syncthreads();
    for (int off = 1; off < SCAN_B; off <<= 1) {
        int v = (t >= off) ? s[t - off] : 0;
        __syncthreads();
        s[t] += v;
        __syncthreads();
    }
    if (t < SCAN_NBLK) blksum[t] = s[t] - c;            // exclusive
}

__global__ void k_scan3(int* row_ptr, const int* __restrict__ blksum,
                        int* cursor, const int* __restrict__ counts, float* dinv) {
    int i = blockIdx.x * blockDim.x + threadIdx.x;
    if (i < N_NODES) {
        int v = row_ptr[i] + blksum[i / SCAN_B];
        row_ptr[i] = v;
        cursor[i] = v;
        dinv[i] = rsqrtf((float)counts[i]);
    }
    if (i == 0) row_ptr[N_NODES] = TOT_E;
}

__global__ void k_fill(const int* __restrict__ src, const int* __restrict__ dst,
                       int* cursor, int* csr_src) {
    int e = blockIdx.x * blockDim.x + threadIdx.x;
    if (e >= TOT_E) return;
    int s, d;
    if (e < N_EDGES) { s = src[e]; d = dst[e]; }
    else             { s = d = e - N_EDGES; }
    int pos = atomicAdd(&cursor[d], 1);
    csr_src[pos] = s;
}

// ================= aggregation kernels: out[d] = dinv[d] * sum_e dinv[s]*f(h[s]) ====

// width 3 (layer-1 input x, L2-resident): one thread per node
__global__ void k_agg3(const float* __restrict__ x, const int* __restrict__ row_ptr,
                       const int* __restrict__ csr_src, const float* __restrict__ dinv,
                       float* __restrict__ out) {
    int n = blockIdx.x * blockDim.x + threadIdx.x;
    if (n >= N_NODES) return;
    int lo = row_ptr[n], hi = row_ptr[n + 1];
    float a0 = 0.f, a1 = 0.f, a2 = 0.f;
    for (int i = lo; i < hi; ++i) {
        int s = csr_src[i];
        float w = dinv[s];
        a0 += x[s * 3 + 0] * w;
        a1 += x[s * 3 + 1] * w;
        a2 += x[s * 3 + 2] * w;
    }
    float din = dinv[n];
    out[n * 3 + 0] = a0 * din;
    out[n * 3 + 1] = a1 * din;
    out[n * 3 + 2] = a2 * din;
}

// width 64: one wave per node, lane = feature; edge idx+norm broadcast via shfl
template<bool RELU_IN>
__global__ void k_agg64(const float* __restrict__ hw, const int* __restrict__ row_ptr,
                        const int* __restrict__ csr_src, const float* __restrict__ dinv,
                        float* __restrict__ out) {
    int wv = (blockIdx.x * blockDim.x + threadIdx.x) >> 6;
    int lane = threadIdx.x & 63;
    if (wv >= N_NODES) return;
    int lo = row_ptr[wv], hi = row_ptr[wv + 1];
    float acc = 0.f;
    for (int base = lo; base < hi; base += 64) {
        int idx = base + lane;
        int sv = csr_src[idx < hi ? idx : hi - 1];
        float dv = dinv[sv];
        int cnt = (hi - base < 64) ? (hi - base) : 64;
#pragma unroll 4
        for (int j = 0; j < cnt; ++j) {
            int s = __shfl(sv, j);
            float w = __shfl(dv, j);
            float v = hw[(size_t)s * 64 + lane];
            if (RELU_IN) v = fmaxf(v, 0.f);
            acc += v * w;
        }
    }
    out[(size_t)wv * 64 + lane] = acc * dinv[wv];
}

// width 128: one wave per node, lane = float2 pair
template<bool RELU_IN>
__global__ void k_agg128(const float* __restrict__ hw, const int* __restrict__ row_ptr,
                         const int* __restrict__ csr_src, const float* __restrict__ dinv,
                         float* __restrict__ out) {
    int wv = (blockIdx.x * blockDim.x + threadIdx.x) >> 6;
    int lane = threadIdx.x & 63;
    if (wv >= N_NODES) return;
    int lo = row_ptr[wv], hi = row_ptr[wv + 1];
    float accx = 0.f, accy = 0.f;
    for (int base = lo; base < hi; base += 64) {
        int idx = base + lane;
        int sv = csr_src[idx < hi ? idx : hi - 1];
        float dv = dinv[sv];
        int cnt = (hi - base < 64) ? (hi - base) : 64;
#pragma unroll 4
        for (int j = 0; j < cnt; ++j) {
            int s = __shfl(sv, j);
            float w = __shfl(dv, j);
            float2 v = *(const float2*)(hw + (size_t)s * 128 + 2 * lane);
            if (RELU_IN) { v.x = fmaxf(v.x, 0.f); v.y = fmaxf(v.y, 0.f); }
            accx += v.x * w;
            accy += v.y * w;
        }
    }
    float din = dinv[wv];
    float2 o; o.x = accx * din; o.y = accy * din;
    *(float2*)(out + (size_t)wv * 128 + 2 * lane) = o;
}

// ================= layer-1 GEMM (K=3) + bias ==============

template<int IN_W, int OUT_W, int NPB>
__global__ void k_node_gemm(const float* __restrict__ h, const float* __restrict__ W,
                            const float* __restrict__ b, float* __restrict__ out) {
    __shared__ float rows[NPB][IN_W];
    int n0 = blockIdx.x * NPB;
    int j = threadIdx.x;                         // blockDim.x == OUT_W
    for (int t = j; t < NPB * IN_W; t += OUT_W) {
        int m = t / IN_W, k = t - m * IN_W;
        int n = n0 + m;
        rows[m][k] = (n < N_NODES) ? h[(size_t)n * IN_W + k] : 0.0f;
    }
    __syncthreads();
    float acc[NPB];
    float bj = b[j];
#pragma unroll
    for (int m = 0; m < NPB; ++m) acc[m] = bj;
#pragma unroll
    for (int k = 0; k < IN_W; ++k) {
        float wk = W[k * OUT_W + j];
#pragma unroll
        for (int m = 0; m < NPB; ++m) acc[m] += rows[m][k] * wk;
    }
#pragma unroll
    for (int m = 0; m < NPB; ++m) {
        int n = n0 + m;
        if (n < N_NODES) out[(size_t)n * OUT_W + j] = acc[m];
    }
}

// ================= tiled GEMM: C[Mx128] = A[MxK] @ W[Kx128] + b =========

#define GM 64
#define GKC 32

template<int K>
__global__ __launch_bounds__(256) void k_gemm128(const float* __restrict__ A,
                                                 const float* __restrict__ W,
                                                 const float* __restrict__ b,
                                                 float* __restrict__ C) {
    __shared__ __align__(16) float sA[GM][GKC];    // 8 KB
    __shared__ __align__(16) float sW[GKC][128];   // 16 KB
    int n0 = blockIdx.x * GM;
    int tid = threadIdx.x;
    int tj = tid & 31;          // cols 4*tj .. 4*tj+3
    int tn = tid >> 5;          // rows 8*tn .. 8*tn+7

    float acc[8][4];
#pragma unroll
    for (int m = 0; m < 8; ++m)
#pragma unroll
        for (int c = 0; c < 4; ++c) acc[m][c] = 0.0f;

    for (int k0 = 0; k0 < K; k0 += GKC) {
        {
            int r  = tid >> 2;                 // 0..63
            int kq = (tid & 3) * 8;            // 0,8,16,24
            int n  = n0 + r;
            float4 v0 = make_float4(0.f, 0.f, 0.f, 0.f);
            float4 v1 = make_float4(0.f, 0.f, 0.f, 0.f);
            if (n < N_NODES) {
                const float* ap = A + (size_t)n * K + k0 + kq;
                v0 = *(const float4*)ap;
                v1 = *(const float4*)(ap + 4);
            }
            float* sp = &sA[r][kq];
            *(float4*)sp = v0;
            *(float4*)(sp + 4) = v1;
        }
        {
            const float* Wc = W + k0 * 128;
            float* sWf = &sW[0][0];
#pragma unroll
            for (int i = 0; i < 4; ++i) {
                int e = (tid + i * 256) * 4;
                *(float4*)(sWf + e) = *(const float4*)(Wc + e);
            }
        }
        __syncthreads();
#pragma unroll
        for (int kk = 0; kk < GKC; ++kk) {
            float4 w = *(const float4*)&sW[kk][tj * 4];
#pragma unroll
            for (int m = 0; m < 8; ++m) {
                float a = sA[tn * 8 + m][kk];
                acc[m][0] += a * w.x;
                acc[m][1] += a * w.y;
                acc[m][2] += a * w.z;
                acc[m][3] += a * w.w;
            }
        }
        __syncthreads();
    }
    float4 bv = *(const float4*)(b + tj * 4);
#pragma unroll
    for (int m = 0; m < 8; ++m) {
        int n = n0 + tn * 8 + m;
        if (n < N_NODES) {
            float4 o = make_float4(acc[m][0] + bv.x, acc[m][1] + bv.y,
                                   acc[m][2] + bv.z, acc[m][3] + bv.w);
            *(float4*)(C + (size_t)n * 128 + tj * 4) = o;
        }
    }
}

// ================= pooling (batch sorted -> binary search ranges) ================

__device__ __forceinline__ int lower_bound_batch(const int* __restrict__ batch, int val) {
    int lo = 0, hi = N_NODES;
    while (lo < hi) {
        int mid = (lo + hi) >> 1;
        if (batch[mid] < val) lo = mid + 1; else hi = mid;
    }
    return lo;
}

__global__ void k_pool_zero(float* pooled, float* cnts) {
    int i = blockIdx.x * blockDim.x + threadIdx.x;
    if (i < N_GRAPHS * 128) pooled[i] = 0.0f;
    if (i < N_GRAPHS) cnts[i] = 0.0f;
}

__global__ void k_pool(const float* __restrict__ h, const int* __restrict__ batch,
                       float* pooled, float* cnts) {
    int g = blockIdx.x / POOL_CHUNKS;
    int c = blockIdx.x - g * POOL_CHUNKS;
    int j = threadIdx.x;
    int lo = lower_bound_batch(batch, g);
    int hi = lower_bound_batch(batch, g + 1);
    int len = hi - lo;
    if (c == 0 && j == 0) cnts[g] = (float)len;
    int s = lo + (int)(((long long)len * c) / POOL_CHUNKS);
    int e = lo + (int)(((long long)len * (c + 1)) / POOL_CHUNKS);
    float acc = 0.0f;
    for (int n = s; n < e; ++n) acc += fmaxf(h[(size_t)n * 128 + j], 0.0f);
    atomicAdd(&pooled[g * 128 + j], acc);
}

// ================= final FC head =================

__global__ void k_fc(const float* __restrict__ pooled, const float* __restrict__ cnts,
                     const float* __restrict__ Wf1, const float* __restrict__ bf1,
                     const float* __restrict__ Wf2, const float* __restrict__ bf2,
                     float* __restrict__ out) {
    __shared__ float sp[128];
    __shared__ float sh1[64];
    int g = blockIdx.x;
    int t = threadIdx.x;             // 128
    float inv = 1.0f / fmaxf(cnts[g], 1.0f);
    sp[t] = pooled[g * 128 + t] * inv;
    __syncthreads();
    if (t < 64) {
        float acc = bf1[t];
#pragma unroll 8
        for (int k = 0; k < 128; ++k) acc += sp[k] * Wf1[k * 64 + t];
        sh1[t] = fmaxf(acc, 0.0f);
    }
    __syncthreads();
    if (t < 10) {
        float acc = bf2[t];
#pragma unroll 8
        for (int k = 0; k < 64; ++k) acc += sh1[k] * Wf2[k * 10 + t];
        out[g * 10 + t] = acc;
    }
}

extern "C" void kernel_launch(void* const* d_in, const int* in_sizes, int n_in,
                              void* d_out, int out_size, void* d_ws, size_t ws_size,
                              hipStream_t stream) {
    const float* x     = (const float*)d_in[0];
    const int*   ei    = (const int*)d_in[1];
    const int*   batch = (const int*)d_in[2];
    const float* W1  = (const float*)d_in[3];
    const float* b1  = (const float*)d_in[4];
    const float* W2  = (const float*)d_in[5];
    const float* b2  = (const float*)d_in[6];
    const float* W3  = (const float*)d_in[7];
    const float* b3  = (const float*)d_in[8];
    const float* Wf1 = (const float*)d_in[9];
    const float* bf1 = (const float*)d_in[10];
    const float* Wf2 = (const float*)d_in[11];
    const float* bf2 = (const float*)d_in[12];
    float* out = (float*)d_out;

    const int* src = ei;              // edge_index[0]
    const int* dst = ei + N_EDGES;    // edge_index[1]

    // workspace layout
    float* dinv   = (float*)d_ws;                      // N
    int*   counts = (int*)(dinv + N_NODES);            // N
    int*   row_ptr= counts + N_NODES;                  // N+1
    int*   blksum = row_ptr + N_NODES + 1;             // 256
    int*   cursor = blksum + 256;                      // N
    int*   csr_src= cursor + N_NODES;                  // TOT_E
    size_t ofs = (size_t)(csr_src + TOT_E) - (size_t)d_ws;
    ofs = (ofs + 15) & ~(size_t)15;                    // 16B align
    float* bufA   = (float*)((char*)d_ws + ofs);       // N*128
    float* bufB   = bufA + (size_t)N_NODES * 128;      // N*128
    float* pooled = bufB + (size_t)N_NODES * 128;      // G*128
    float* cnts   = pooled + N_GRAPHS * 128;           // G

    const int TB = 256;

    // ---- CSR build + norm ----
    k_init_counts<<<(N_NODES + TB - 1) / TB, TB, 0, stream>>>(counts);
    k_hist<<<(N_EDGES + TB - 1) / TB, TB, 0, stream>>>(dst, counts);
    k_scan1<<<SCAN_NBLK, SCAN_B, 0, stream>>>(counts, row_ptr, blksum);
    k_scan2<<<1, SCAN_B, 0, stream>>>(blksum);
    k_scan3<<<(N_NODES + TB - 1) / TB, TB, 0, stream>>>(row_ptr, blksum, cursor, counts, dinv);
    k_fill<<<(TOT_E + TB - 1) / TB, TB, 0, stream>>>(src, dst, cursor, csr_src);

    // ---- layer 1: agg(x) @ W1 + b1 ----   (agg at width 3, L2-resident)
    k_agg3<<<(N_NODES + TB - 1) / TB, TB, 0, stream>>>(x, row_ptr, csr_src, dinv, bufA);
    k_node_gemm<3, 64, 4><<<(N_NODES + 3) / 4, 64, 0, stream>>>(bufA, W1, b1, bufB);

    // ---- layer 2: agg(relu(h1)) @ W2 + b2 ----   (agg at width 64)
    k_agg64<true><<<(N_NODES * 64 + TB - 1) / TB, TB, 0, stream>>>(bufB, row_ptr, csr_src, dinv, bufA);
    k_gemm128<64><<<(N_NODES + GM - 1) / GM, 256, 0, stream>>>(bufA, W2, b2, bufB);

    // ---- layer 3: agg(relu(h2)) @ W3 + b3 ----   (agg at width 128)
    k_agg128<true><<<(N_NODES * 64 + TB - 1) / TB, TB, 0, stream>>>(bufB, row_ptr, csr_src, dinv, bufA);
    k_gemm128<128><<<(N_NODES + GM - 1) / GM, 256, 0, stream>>>(bufA, W3, b3, bufB);

    // ---- global mean pool (relu folded) + FC head ----
    k_pool_zero<<<(N_GRAPHS * 128 + TB - 1) / TB, TB, 0, stream>>>(pooled, cnts);
    k_pool<<<N_GRAPHS * POOL_CHUNKS, 128, 0, stream>>>(bufB, batch, pooled, cnts);
    k_fc<<<N_GRAPHS, 128, 0, stream>>>(pooled, cnts, Wf1, bf1, Wf2, bf2, out);
}

// Round 6
// 408.164 us; speedup vs baseline: 9.2716x; 1.0566x over previous
//
#include <hip/hip_runtime.h>

#define N_NODES 50000
#define N_EDGES 800000
#define N_GRAPHS 64
#define POOL_CHUNKS 8
#define TOT_E (N_EDGES + N_NODES)
#define SCAN_B 256
#define SCAN_NBLK ((N_NODES + SCAN_B - 1) / SCAN_B)   // 196

// fp32 -> bf16 round-to-nearest-even
__device__ __forceinline__ unsigned short f2bf(float f) {
    unsigned int u = __float_as_uint(f);
    u += 0x7FFFu + ((u >> 16) & 1u);
    return (unsigned short)(u >> 16);
}
__device__ __forceinline__ float bf2f(unsigned short h) {
    return __uint_as_float(((unsigned int)h) << 16);
}

// ================= CSR build =================
// counts zeroed via hipMemsetAsync; degree = counts + 1 (self-loop)

__global__ void k_hist(const int* __restrict__ dst, int* counts) {
    int i = blockIdx.x * blockDim.x + threadIdx.x;
    if (i < N_EDGES) atomicAdd(&counts[dst[i]], 1);
}

__global__ void k_scan1(const int* __restrict__ counts, int* row_ptr, int* blksum) {
    __shared__ int s[SCAN_B];
    int i = blockIdx.x * SCAN_B + threadIdx.x;
    int c = (i < N_NODES) ? (counts[i] + 1) : 0;
    s[threadIdx.x] = c;
    __syncthreads();
    for (int off = 1; off < SCAN_B; off <<= 1) {
        int v = (threadIdx.x >= off) ? s[threadIdx.x - off] : 0;
        __syncthreads();
        s[threadIdx.x] += v;
        __syncthreads();
    }
    if (i < N_NODES) row_ptr[i] = s[threadIdx.x] - c;   // exclusive
    if (threadIdx.x == SCAN_B - 1) blksum[blockIdx.x] = s[SCAN_B - 1];
}

__global__ void k_scan2(int* blksum) {
    __shared__ int s[SCAN_B];
    int t = threadIdx.x;
    int c = (t < SCAN_NBLK) ? blksum[t] : 0;
    s[t] = c;
    __syncthreads();
    for (int off = 1; off < SCAN_B; off <<= 1) {
        int v = (t >= off) ? s[t - off] : 0;
        __syncthreads();
        s[t] += v;
        __syncthreads();
    }
    if (t < SCAN_NBLK) blksum[t] = s[t] - c;            // exclusive
}

// finalize row_ptr, init cursor, dinv = rsqrt(deg), xs = x * dinv (pre-scaled layer-1 input)
__global__ void k_scan3(int* row_ptr, const int* __restrict__ blksum,
                        int* cursor, const int* __restrict__ counts, float* dinv,
                        const float* __restrict__ x, float* __restrict__ xs) {
    int i = blockIdx.x * blockDim.x + threadIdx.x;
    if (i < N_NODES) {
        int v = row_ptr[i] + blksum[i / SCAN_B];
        row_ptr[i] = v;
        cursor[i] = v;
        float di = rsqrtf((float)(counts[i] + 1));
        dinv[i] = di;
        xs[i * 3 + 0] = x[i * 3 + 0] * di;
        xs[i * 3 + 1] = x[i * 3 + 1] * di;
        xs[i * 3 + 2] = x[i * 3 + 2] * di;
    }
    if (i == 0) row_ptr[N_NODES] = TOT_E;
}

__global__ void k_fill(const int* __restrict__ src, const int* __restrict__ dst,
                       int* cursor, int* csr_src) {
    int e = blockIdx.x * blockDim.x + threadIdx.x;
    if (e >= TOT_E) return;
    int s, d;
    if (e < N_EDGES) { s = src[e]; d = dst[e]; }
    else             { s = d = e - N_EDGES; }
    int pos = atomicAdd(&cursor[d], 1);
    csr_src[pos] = s;
}

// ================= aggregation: out[d] = dinv[d] * sum_e hs[src]  (hs pre-scaled) ====

// width 3 (xs, L2-resident): one thread per node
__global__ void k_agg3(const float* __restrict__ xs, const int* __restrict__ row_ptr,
                       const int* __restrict__ csr_src, const float* __restrict__ dinv,
                       float* __restrict__ out) {
    int n = blockIdx.x * blockDim.x + threadIdx.x;
    if (n >= N_NODES) return;
    int lo = row_ptr[n], hi = row_ptr[n + 1];
    float a0 = 0.f, a1 = 0.f, a2 = 0.f;
    for (int i = lo; i < hi; ++i) {
        int s = csr_src[i];
        a0 += xs[s * 3 + 0];
        a1 += xs[s * 3 + 1];
        a2 += xs[s * 3 + 2];
    }
    float din = dinv[n];
    out[n * 3 + 0] = a0 * din;
    out[n * 3 + 1] = a1 * din;
    out[n * 3 + 2] = a2 * din;
}

// width 64 bf16: one wave per node, lane = feature
__global__ void k_agg64(const unsigned short* __restrict__ hb, const int* __restrict__ row_ptr,
                        const int* __restrict__ csr_src, const float* __restrict__ dinv,
                        float* __restrict__ out) {
    int wv = (blockIdx.x * blockDim.x + threadIdx.x) >> 6;
    int lane = threadIdx.x & 63;
    if (wv >= N_NODES) return;
    int lo = row_ptr[wv], hi = row_ptr[wv + 1];
    float acc = 0.f;
    for (int base = lo; base < hi; base += 64) {
        int idx = base + lane;
        int sv = csr_src[idx < hi ? idx : hi - 1];
        int cnt = (hi - base < 64) ? (hi - base) : 64;
#pragma unroll 4
        for (int j = 0; j < cnt; ++j) {
            int s = __shfl(sv, j);
            acc += bf2f(hb[(size_t)s * 64 + lane]);
        }
    }
    out[(size_t)wv * 64 + lane] = acc * dinv[wv];
}

// width 128 bf16: one wave per node, lane = bf16x2 pair (uint load)
__global__ void k_agg128(const unsigned short* __restrict__ hb, const int* __restrict__ row_ptr,
                         const int* __restrict__ csr_src, const float* __restrict__ dinv,
                         float* __restrict__ out) {
    int wv = (blockIdx.x * blockDim.x + threadIdx.x) >> 6;
    int lane = threadIdx.x & 63;
    if (wv >= N_NODES) return;
    int lo = row_ptr[wv], hi = row_ptr[wv + 1];
    float accx = 0.f, accy = 0.f;
    for (int base = lo; base < hi; base += 64) {
        int idx = base + lane;
        int sv = csr_src[idx < hi ? idx : hi - 1];
        int cnt = (hi - base < 64) ? (hi - base) : 64;
#pragma unroll 4
        for (int j = 0; j < cnt; ++j) {
            int s = __shfl(sv, j);
            unsigned int u = ((const unsigned int*)(hb + (size_t)s * 128))[lane];
            accx += __uint_as_float(u << 16);
            accy += __uint_as_float(u & 0xffff0000u);
        }
    }
    float din = dinv[wv];
    float2 o; o.x = accx * din; o.y = accy * din;
    *(float2*)(out + (size_t)wv * 128 + 2 * lane) = o;
}

// ================= layer-1 GEMM (K=3) + bias; epilogue: bf16(dinv*relu(.)) ==========

template<int IN_W, int OUT_W, int NPB>
__global__ void k_node_gemm(const float* __restrict__ h, const float* __restrict__ W,
                            const float* __restrict__ b, const float* __restrict__ dinv,
                            unsigned short* __restrict__ hb) {
    __shared__ float rows[NPB][IN_W];
    int n0 = blockIdx.x * NPB;
    int j = threadIdx.x;                         // blockDim.x == OUT_W
    for (int t = j; t < NPB * IN_W; t += OUT_W) {
        int m = t / IN_W, k = t - m * IN_W;
        int n = n0 + m;
        rows[m][k] = (n < N_NODES) ? h[(size_t)n * IN_W + k] : 0.0f;
    }
    __syncthreads();
    float acc[NPB];
    float bj = b[j];
#pragma unroll
    for (int m = 0; m < NPB; ++m) acc[m] = bj;
#pragma unroll
    for (int k = 0; k < IN_W; ++k) {
        float wk = W[k * OUT_W + j];
#pragma unroll
        for (int m = 0; m < NPB; ++m) acc[m] += rows[m][k] * wk;
    }
#pragma unroll
    for (int m = 0; m < NPB; ++m) {
        int n = n0 + m;
        if (n < N_NODES)
            hb[(size_t)n * OUT_W + j] = f2bf(fmaxf(acc[m], 0.0f) * dinv[n]);
    }
}

// ================= tiled GEMM: C = A[MxK] @ W[Kx128] + b ==========
// BF16OUT: write bf16(dinv*relu(.)) to hb; else raw fp32 (+bias) to C.

#define GM 64
#define GKC 32

template<int K, bool BF16OUT>
__global__ __launch_bounds__(256) void k_gemm128(const float* __restrict__ A,
                                                 const float* __restrict__ W,
                                                 const float* __restrict__ b,
                                                 const float* __restrict__ dinv,
                                                 float* __restrict__ C,
                                                 unsigned short* __restrict__ hb) {
    __shared__ __align__(16) float sA[GM][GKC];    // 8 KB
    __shared__ __align__(16) float sW[GKC][128];   // 16 KB
    int n0 = blockIdx.x * GM;
    int tid = threadIdx.x;
    int tj = tid & 31;          // cols 4*tj .. 4*tj+3
    int tn = tid >> 5;          // rows 8*tn .. 8*tn+7

    float acc[8][4];
#pragma unroll
    for (int m = 0; m < 8; ++m)
#pragma unroll
        for (int c = 0; c < 4; ++c) acc[m][c] = 0.0f;

    for (int k0 = 0; k0 < K; k0 += GKC) {
        {
            int r  = tid >> 2;                 // 0..63
            int kq = (tid & 3) * 8;            // 0,8,16,24
            int n  = n0 + r;
            float4 v0 = make_float4(0.f, 0.f, 0.f, 0.f);
            float4 v1 = make_float4(0.f, 0.f, 0.f, 0.f);
            if (n < N_NODES) {
                const float* ap = A + (size_t)n * K + k0 + kq;
                v0 = *(const float4*)ap;
                v1 = *(const float4*)(ap + 4);
            }
            float* sp = &sA[r][kq];
            *(float4*)sp = v0;
            *(float4*)(sp + 4) = v1;
        }
        {
            const float* Wc = W + k0 * 128;
            float* sWf = &sW[0][0];
#pragma unroll
            for (int i = 0; i < 4; ++i) {
                int e = (tid + i * 256) * 4;
                *(float4*)(sWf + e) = *(const float4*)(Wc + e);
            }
        }
        __syncthreads();
#pragma unroll
        for (int kk = 0; kk < GKC; ++kk) {
            float4 w = *(const float4*)&sW[kk][tj * 4];
#pragma unroll
            for (int m = 0; m < 8; ++m) {
                float a = sA[tn * 8 + m][kk];
                acc[m][0] += a * w.x;
                acc[m][1] += a * w.y;
                acc[m][2] += a * w.z;
                acc[m][3] += a * w.w;
            }
        }
        __syncthreads();
    }
    float4 bv = *(const float4*)(b + tj * 4);
#pragma unroll
    for (int m = 0; m < 8; ++m) {
        int n = n0 + tn * 8 + m;
        if (n < N_NODES) {
            float o0 = acc[m][0] + bv.x, o1 = acc[m][1] + bv.y;
            float o2 = acc[m][2] + bv.z, o3 = acc[m][3] + bv.w;
            if (BF16OUT) {
                float di = dinv[n];
                unsigned short h0 = f2bf(fmaxf(o0, 0.f) * di);
                unsigned short h1 = f2bf(fmaxf(o1, 0.f) * di);
                unsigned short h2 = f2bf(fmaxf(o2, 0.f) * di);
                unsigned short h3 = f2bf(fmaxf(o3, 0.f) * di);
                uint2 w2;
                w2.x = (unsigned int)h0 | ((unsigned int)h1 << 16);
                w2.y = (unsigned int)h2 | ((unsigned int)h3 << 16);
                *(uint2*)(hb + (size_t)n * 128 + tj * 4) = w2;
            } else {
                *(float4*)(C + (size_t)n * 128 + tj * 4) = make_float4(o0, o1, o2, o3);
            }
        }
    }
}

// ================= pooling (batch sorted -> binary search ranges) ================

__device__ __forceinline__ int lower_bound_batch(const int* __restrict__ batch, int val) {
    int lo = 0, hi = N_NODES;
    while (lo < hi) {
        int mid = (lo + hi) >> 1;
        if (batch[mid] < val) lo = mid + 1; else hi = mid;
    }
    return lo;
}

__global__ void k_pool_zero(float* pooled, float* cnts) {
    int i = blockIdx.x * blockDim.x + threadIdx.x;
    if (i < N_GRAPHS * 128) pooled[i] = 0.0f;
    if (i < N_GRAPHS) cnts[i] = 0.0f;
}

__global__ void k_pool(const float* __restrict__ h, const int* __restrict__ batch,
                       float* pooled, float* cnts) {
    int g = blockIdx.x / POOL_CHUNKS;
    int c = blockIdx.x - g * POOL_CHUNKS;
    int j = threadIdx.x;
    int lo = lower_bound_batch(batch, g);
    int hi = lower_bound_batch(batch, g + 1);
    int len = hi - lo;
    if (c == 0 && j == 0) cnts[g] = (float)len;
    int s = lo + (int)(((long long)len * c) / POOL_CHUNKS);
    int e = lo + (int)(((long long)len * (c + 1)) / POOL_CHUNKS);
    float acc = 0.0f;
    for (int n = s; n < e; ++n) acc += fmaxf(h[(size_t)n * 128 + j], 0.0f);
    atomicAdd(&pooled[g * 128 + j], acc);
}

// ================= final FC head =================

__global__ void k_fc(const float* __restrict__ pooled, const float* __restrict__ cnts,
                     const float* __restrict__ Wf1, const float* __restrict__ bf1,
                     const float* __restrict__ Wf2, const float* __restrict__ bf2,
                     float* __restrict__ out) {
    __shared__ float sp[128];
    __shared__ float sh1[64];
    int g = blockIdx.x;
    int t = threadIdx.x;             // 128
    float inv = 1.0f / fmaxf(cnts[g], 1.0f);
    sp[t] = pooled[g * 128 + t] * inv;
    __syncthreads();
    if (t < 64) {
        float acc = bf1[t];
#pragma unroll 8
        for (int k = 0; k < 128; ++k) acc += sp[k] * Wf1[k * 64 + t];
        sh1[t] = fmaxf(acc, 0.0f);
    }
    __syncthreads();
    if (t < 10) {
        float acc = bf2[t];
#pragma unroll 8
        for (int k = 0; k < 64; ++k) acc += sh1[k] * Wf2[k * 10 + t];
        out[g * 10 + t] = acc;
    }
}

extern "C" void kernel_launch(void* const* d_in, const int* in_sizes, int n_in,
                              void* d_out, int out_size, void* d_ws, size_t ws_size,
                              hipStream_t stream) {
    const float* x     = (const float*)d_in[0];
    const int*   ei    = (const int*)d_in[1];
    const int*   batch = (const int*)d_in[2];
    const float* W1  = (const float*)d_in[3];
    const float* b1  = (const float*)d_in[4];
    const float* W2  = (const float*)d_in[5];
    const float* b2  = (const float*)d_in[6];
    const float* W3  = (const float*)d_in[7];
    const float* b3  = (const float*)d_in[8];
    const float* Wf1 = (const float*)d_in[9];
    const float* bf1 = (const float*)d_in[10];
    const float* Wf2 = (const float*)d_in[11];
    const float* bf2 = (const float*)d_in[12];
    float* out = (float*)d_out;

    const int* src = ei;              // edge_index[0]
    const int* dst = ei + N_EDGES;    // edge_index[1]

    // workspace layout
    float* dinv   = (float*)d_ws;                      // N
    int*   counts = (int*)(dinv + N_NODES);            // N
    int*   row_ptr= counts + N_NODES;                  // N+1
    int*   blksum = row_ptr + N_NODES + 1;             // 256
    int*   cursor = blksum + 256;                      // N
    int*   csr_src= cursor + N_NODES;                  // TOT_E
    float* xs     = (float*)(csr_src + TOT_E);         // N*3
    size_t ofs = (size_t)(xs + (size_t)N_NODES * 3) - (size_t)d_ws;
    ofs = (ofs + 15) & ~(size_t)15;                    // 16B align
    float* bufA   = (float*)((char*)d_ws + ofs);       // N*128 fp32
    float* bufB   = bufA + (size_t)N_NODES * 128;      // N*128 fp32 (aliases hb)
    unsigned short* hb = (unsigned short*)bufB;        // N*128 bf16 (dead before bufB written)
    float* pooled = bufB + (size_t)N_NODES * 128;      // G*128
    float* cnts   = pooled + N_GRAPHS * 128;           // G

    const int TB = 256;

    // ---- CSR build + norm + pre-scaled x ----
    hipMemsetAsync(counts, 0, N_NODES * sizeof(int), stream);
    k_hist<<<(N_EDGES + TB - 1) / TB, TB, 0, stream>>>(dst, counts);
    k_scan1<<<SCAN_NBLK, SCAN_B, 0, stream>>>(counts, row_ptr, blksum);
    k_scan2<<<1, SCAN_B, 0, stream>>>(blksum);
    k_scan3<<<(N_NODES + TB - 1) / TB, TB, 0, stream>>>(row_ptr, blksum, cursor, counts, dinv, x, xs);
    k_fill<<<(TOT_E + TB - 1) / TB, TB, 0, stream>>>(src, dst, cursor, csr_src);

    // ---- layer 1: agg(xs) @ W1 + b1 -> hb = bf16(dinv*relu) ----
    k_agg3<<<(N_NODES + TB - 1) / TB, TB, 0, stream>>>(xs, row_ptr, csr_src, dinv, bufA);
    k_node_gemm<3, 64, 4><<<(N_NODES + 3) / 4, 64, 0, stream>>>(bufA, W1, b1, dinv, hb);

    // ---- layer 2: agg64(hb) @ W2 + b2 -> hb = bf16(dinv*relu) ----
    k_agg64<<<(N_NODES * 64 + TB - 1) / TB, TB, 0, stream>>>(hb, row_ptr, csr_src, dinv, bufA);
    k_gemm128<64, true><<<(N_NODES + GM - 1) / GM, 256, 0, stream>>>(bufA, W2, b2, dinv, nullptr, hb);

    // ---- layer 3: agg128(hb) @ W3 + b3 -> bufB fp32 (pool applies relu) ----
    k_agg128<<<(N_NODES * 64 + TB - 1) / TB, TB, 0, stream>>>(hb, row_ptr, csr_src, dinv, bufA);
    k_gemm128<128, false><<<(N_NODES + GM - 1) / GM, 256, 0, stream>>>(bufA, W3, b3, dinv, bufB, nullptr);

    // ---- global mean pool (relu folded) + FC head ----
    k_pool_zero<<<(N_GRAPHS * 128 + TB - 1) / TB, TB, 0, stream>>>(pooled, cnts);
    k_pool<<<N_GRAPHS * POOL_CHUNKS, 128, 0, stream>>>(bufB, batch, pooled, cnts);
    k_fc<<<N_GRAPHS, 128, 0, stream>>>(pooled, cnts, Wf1, bf1, Wf2, bf2, out);
}

// Round 7
// 376.029 us; speedup vs baseline: 10.0639x; 1.0855x over previous
//
#include <hip/hip_runtime.h>

#define N_NODES 50000
#define N_EDGES 800000
#define N_GRAPHS 64
#define TOT_E (N_EDGES + N_NODES)
#define SCAN_B 256
#define SCAN_NBLK ((N_NODES + SCAN_B - 1) / SCAN_B)   // 196

// fp32 -> bf16 round-to-nearest-even
__device__ __forceinline__ unsigned short f2bf(float f) {
    unsigned int u = __float_as_uint(f);
    u += 0x7FFFu + ((u >> 16) & 1u);
    return (unsigned short)(u >> 16);
}
__device__ __forceinline__ float bf2f(unsigned short h) {
    return __uint_as_float(((unsigned int)h) << 16);
}

// ================= CSR build =================
// counts zeroed via hipMemsetAsync; degree = counts + 1 (self-loop)

__global__ void k_hist(const int* __restrict__ dst, int* counts) {
    int i = blockIdx.x * blockDim.x + threadIdx.x;
    if (i < N_EDGES) atomicAdd(&counts[dst[i]], 1);
}

__global__ void k_scan1(const int* __restrict__ counts, int* row_ptr, int* blksum) {
    __shared__ int s[SCAN_B];
    int i = blockIdx.x * SCAN_B + threadIdx.x;
    int c = (i < N_NODES) ? (counts[i] + 1) : 0;
    s[threadIdx.x] = c;
    __syncthreads();
    for (int off = 1; off < SCAN_B; off <<= 1) {
        int v = (threadIdx.x >= off) ? s[threadIdx.x - off] : 0;
        __syncthreads();
        s[threadIdx.x] += v;
        __syncthreads();
    }
    if (i < N_NODES) row_ptr[i] = s[threadIdx.x] - c;   // exclusive
    if (threadIdx.x == SCAN_B - 1) blksum[blockIdx.x] = s[SCAN_B - 1];
}

__global__ void k_scan2(int* blksum) {
    __shared__ int s[SCAN_B];
    int t = threadIdx.x;
    int c = (t < SCAN_NBLK) ? blksum[t] : 0;
    s[t] = c;
    __syncthreads();
    for (int off = 1; off < SCAN_B; off <<= 1) {
        int v = (t >= off) ? s[t - off] : 0;
        __syncthreads();
        s[t] += v;
        __syncthreads();
    }
    if (t < SCAN_NBLK) blksum[t] = s[t] - c;            // exclusive
}

// finalize row_ptr, init cursor, dinv = rsqrt(deg), xs = x * dinv
__global__ void k_scan3(int* row_ptr, const int* __restrict__ blksum,
                        int* cursor, const int* __restrict__ counts, float* dinv,
                        const float* __restrict__ x, float* __restrict__ xs) {
    int i = blockIdx.x * blockDim.x + threadIdx.x;
    if (i < N_NODES) {
        int v = row_ptr[i] + blksum[i / SCAN_B];
        row_ptr[i] = v;
        cursor[i] = v;
        float di = rsqrtf((float)(counts[i] + 1));
        dinv[i] = di;
        xs[i * 3 + 0] = x[i * 3 + 0] * di;
        xs[i * 3 + 1] = x[i * 3 + 1] * di;
        xs[i * 3 + 2] = x[i * 3 + 2] * di;
    }
    if (i == 0) row_ptr[N_NODES] = TOT_E;
}

__global__ void k_fill(const int* __restrict__ src, const int* __restrict__ dst,
                       int* cursor, int* csr_src) {
    int e = blockIdx.x * blockDim.x + threadIdx.x;
    if (e >= TOT_E) return;
    int s, d;
    if (e < N_EDGES) { s = src[e]; d = dst[e]; }
    else             { s = d = e - N_EDGES; }
    int pos = atomicAdd(&cursor[d], 1);
    csr_src[pos] = s;
}

// ================= aggregation: out[d] = dinv[d] * sum_e hs[src]  (hs pre-scaled) ====

__global__ void k_agg3(const float* __restrict__ xs, const int* __restrict__ row_ptr,
                       const int* __restrict__ csr_src, const float* __restrict__ dinv,
                       float* __restrict__ out) {
    int n = blockIdx.x * blockDim.x + threadIdx.x;
    if (n >= N_NODES) return;
    int lo = row_ptr[n], hi = row_ptr[n + 1];
    float a0 = 0.f, a1 = 0.f, a2 = 0.f;
    for (int i = lo; i < hi; ++i) {
        int s = csr_src[i];
        a0 += xs[s * 3 + 0];
        a1 += xs[s * 3 + 1];
        a2 += xs[s * 3 + 2];
    }
    float din = dinv[n];
    out[n * 3 + 0] = a0 * din;
    out[n * 3 + 1] = a1 * din;
    out[n * 3 + 2] = a2 * din;
}

// width 64 bf16: one wave per node, lane = feature
__global__ void k_agg64(const unsigned short* __restrict__ hb, const int* __restrict__ row_ptr,
                        const int* __restrict__ csr_src, const float* __restrict__ dinv,
                        float* __restrict__ out) {
    int wv = (blockIdx.x * blockDim.x + threadIdx.x) >> 6;
    int lane = threadIdx.x & 63;
    if (wv >= N_NODES) return;
    int lo = row_ptr[wv], hi = row_ptr[wv + 1];
    float acc = 0.f;
    for (int base = lo; base < hi; base += 64) {
        int idx = base + lane;
        int sv = csr_src[idx < hi ? idx : hi - 1];
        int cnt = (hi - base < 64) ? (hi - base) : 64;
#pragma unroll 8
        for (int j = 0; j < cnt; ++j) {
            int s = __shfl(sv, j);
            acc += bf2f(hb[(size_t)s * 64 + lane]);
        }
    }
    out[(size_t)wv * 64 + lane] = acc * dinv[wv];
}

// width 128 bf16: one wave per node, lane = bf16x2 pair (uint load)
__global__ void k_agg128(const unsigned short* __restrict__ hb, const int* __restrict__ row_ptr,
                         const int* __restrict__ csr_src, const float* __restrict__ dinv,
                         float* __restrict__ out) {
    int wv = (blockIdx.x * blockDim.x + threadIdx.x) >> 6;
    int lane = threadIdx.x & 63;
    if (wv >= N_NODES) return;
    int lo = row_ptr[wv], hi = row_ptr[wv + 1];
    float accx = 0.f, accy = 0.f;
    for (int base = lo; base < hi; base += 64) {
        int idx = base + lane;
        int sv = csr_src[idx < hi ? idx : hi - 1];
        int cnt = (hi - base < 64) ? (hi - base) : 64;
#pragma unroll 8
        for (int j = 0; j < cnt; ++j) {
            int s = __shfl(sv, j);
            unsigned int u = ((const unsigned int*)(hb + (size_t)s * 128))[lane];
            accx += __uint_as_float(u << 16);
            accy += __uint_as_float(u & 0xffff0000u);
        }
    }
    float din = dinv[wv];
    float2 o; o.x = accx * din; o.y = accy * din;
    *(float2*)(out + (size_t)wv * 128 + 2 * lane) = o;
}

// ================= layer-1 GEMM (K=3) + bias; epilogue: bf16(dinv*relu(.)) ==========

template<int IN_W, int OUT_W, int NPB>
__global__ void k_node_gemm(const float* __restrict__ h, const float* __restrict__ W,
                            const float* __restrict__ b, const float* __restrict__ dinv,
                            unsigned short* __restrict__ hb) {
    __shared__ float rows[NPB][IN_W];
    int n0 = blockIdx.x * NPB;
    int j = threadIdx.x;                         // blockDim.x == OUT_W
    for (int t = j; t < NPB * IN_W; t += OUT_W) {
        int m = t / IN_W, k = t - m * IN_W;
        int n = n0 + m;
        rows[m][k] = (n < N_NODES) ? h[(size_t)n * IN_W + k] : 0.0f;
    }
    __syncthreads();
    float acc[NPB];
    float bj = b[j];
#pragma unroll
    for (int m = 0; m < NPB; ++m) acc[m] = bj;
#pragma unroll
    for (int k = 0; k < IN_W; ++k) {
        float wk = W[k * OUT_W + j];
#pragma unroll
        for (int m = 0; m < NPB; ++m) acc[m] += rows[m][k] * wk;
    }
#pragma unroll
    for (int m = 0; m < NPB; ++m) {
        int n = n0 + m;
        if (n < N_NODES)
            hb[(size_t)n * OUT_W + j] = f2bf(fmaxf(acc[m], 0.0f) * dinv[n]);
    }
}

// ================= tiled GEMM (K=64): epilogue bf16(dinv*relu(.)) -> hb ==========

#define GM 64
#define GKC 32

__global__ __launch_bounds__(256) void k_gemm_l2(const float* __restrict__ A,
                                                 const float* __restrict__ W,
                                                 const float* __restrict__ b,
                                                 const float* __restrict__ dinv,
                                                 unsigned short* __restrict__ hb) {
    const int K = 64;
    __shared__ __align__(16) float sA[GM][GKC];
    __shared__ __align__(16) float sW[GKC][128];
    int n0 = blockIdx.x * GM;
    int tid = threadIdx.x;
    int tj = tid & 31;
    int tn = tid >> 5;

    float acc[8][4];
#pragma unroll
    for (int m = 0; m < 8; ++m)
#pragma unroll
        for (int c = 0; c < 4; ++c) acc[m][c] = 0.0f;

    for (int k0 = 0; k0 < K; k0 += GKC) {
        {
            int r  = tid >> 2;
            int kq = (tid & 3) * 8;
            int n  = n0 + r;
            float4 v0 = make_float4(0.f, 0.f, 0.f, 0.f);
            float4 v1 = make_float4(0.f, 0.f, 0.f, 0.f);
            if (n < N_NODES) {
                const float* ap = A + (size_t)n * K + k0 + kq;
                v0 = *(const float4*)ap;
                v1 = *(const float4*)(ap + 4);
            }
            float* sp = &sA[r][kq];
            *(float4*)sp = v0;
            *(float4*)(sp + 4) = v1;
        }
        {
            const float* Wc = W + k0 * 128;
            float* sWf = &sW[0][0];
#pragma unroll
            for (int i = 0; i < 4; ++i) {
                int e = (tid + i * 256) * 4;
                *(float4*)(sWf + e) = *(const float4*)(Wc + e);
            }
        }
        __syncthreads();
#pragma unroll
        for (int kk = 0; kk < GKC; ++kk) {
            float4 w = *(const float4*)&sW[kk][tj * 4];
#pragma unroll
            for (int m = 0; m < 8; ++m) {
                float a = sA[tn * 8 + m][kk];
                acc[m][0] += a * w.x;
                acc[m][1] += a * w.y;
                acc[m][2] += a * w.z;
                acc[m][3] += a * w.w;
            }
        }
        __syncthreads();
    }
    float4 bv = *(const float4*)(b + tj * 4);
#pragma unroll
    for (int m = 0; m < 8; ++m) {
        int n = n0 + tn * 8 + m;
        if (n < N_NODES) {
            float di = dinv[n];
            unsigned short h0 = f2bf(fmaxf(acc[m][0] + bv.x, 0.f) * di);
            unsigned short h1 = f2bf(fmaxf(acc[m][1] + bv.y, 0.f) * di);
            unsigned short h2 = f2bf(fmaxf(acc[m][2] + bv.z, 0.f) * di);
            unsigned short h3 = f2bf(fmaxf(acc[m][3] + bv.w, 0.f) * di);
            uint2 w2;
            w2.x = (unsigned int)h0 | ((unsigned int)h1 << 16);
            w2.y = (unsigned int)h2 | ((unsigned int)h3 << 16);
            *(uint2*)(hb + (size_t)n * 128 + tj * 4) = w2;
        }
    }
}

// ================= layer-3 GEMM (K=128) with fused mean-pool epilogue ==========
// batch is sorted; a 64-row tile spans few graphs. Per graph: LDS-reduce
// relu(acc+bias) over the tile's rows, then 128 atomics into pooled[g].

__global__ __launch_bounds__(256) void k_gemm_l3_pool(const float* __restrict__ A,
                                                      const float* __restrict__ W,
                                                      const float* __restrict__ b,
                                                      const int* __restrict__ batch,
                                                      float* __restrict__ pooled) {
    const int K = 128;
    __shared__ __align__(16) float sA[GM][GKC];
    __shared__ __align__(16) float sW[GKC][128];
    __shared__ float red[8][128];
    __shared__ int sb[GM];
    int n0 = blockIdx.x * GM;
    int tid = threadIdx.x;
    int tj = tid & 31;
    int tn = tid >> 5;

    float acc[8][4];
#pragma unroll
    for (int m = 0; m < 8; ++m)
#pragma unroll
        for (int c = 0; c < 4; ++c) acc[m][c] = 0.0f;

    for (int k0 = 0; k0 < K; k0 += GKC) {
        {
            int r  = tid >> 2;
            int kq = (tid & 3) * 8;
            int n  = n0 + r;
            float4 v0 = make_float4(0.f, 0.f, 0.f, 0.f);
            float4 v1 = make_float4(0.f, 0.f, 0.f, 0.f);
            if (n < N_NODES) {
                const float* ap = A + (size_t)n * K + k0 + kq;
                v0 = *(const float4*)ap;
                v1 = *(const float4*)(ap + 4);
            }
            float* sp = &sA[r][kq];
            *(float4*)sp = v0;
            *(float4*)(sp + 4) = v1;
        }
        {
            const float* Wc = W + k0 * 128;
            float* sWf = &sW[0][0];
#pragma unroll
            for (int i = 0; i < 4; ++i) {
                int e = (tid + i * 256) * 4;
                *(float4*)(sWf + e) = *(const float4*)(Wc + e);
            }
        }
        __syncthreads();
#pragma unroll
        for (int kk = 0; kk < GKC; ++kk) {
            float4 w = *(const float4*)&sW[kk][tj * 4];
#pragma unroll
            for (int m = 0; m < 8; ++m) {
                float a = sA[tn * 8 + m][kk];
                acc[m][0] += a * w.x;
                acc[m][1] += a * w.y;
                acc[m][2] += a * w.z;
                acc[m][3] += a * w.w;
            }
        }
        __syncthreads();
    }
    // bias + relu in registers
    float4 bv = *(const float4*)(b + tj * 4);
#pragma unroll
    for (int m = 0; m < 8; ++m) {
        acc[m][0] = fmaxf(acc[m][0] + bv.x, 0.f);
        acc[m][1] = fmaxf(acc[m][1] + bv.y, 0.f);
        acc[m][2] = fmaxf(acc[m][2] + bv.z, 0.f);
        acc[m][3] = fmaxf(acc[m][3] + bv.w, 0.f);
    }
    // stage per-row graph ids (-1 for rows past N_NODES)
    if (tid < GM) {
        int n = n0 + tid;
        sb[tid] = (n < N_NODES) ? batch[n] : -1;
    }
    __syncthreads();
    int g0 = sb[0];
    int last = (n0 + GM - 1 < N_NODES) ? (n0 + GM - 1) : (N_NODES - 1);
    int g1 = batch[last];
    for (int g = g0; g <= g1; ++g) {
        float p0 = 0.f, p1 = 0.f, p2 = 0.f, p3 = 0.f;
#pragma unroll
        for (int m = 0; m < 8; ++m) {
            if (sb[tn * 8 + m] == g) {
                p0 += acc[m][0]; p1 += acc[m][1];
                p2 += acc[m][2]; p3 += acc[m][3];
            }
        }
        red[tn][tj * 4 + 0] = p0;
        red[tn][tj * 4 + 1] = p1;
        red[tn][tj * 4 + 2] = p2;
        red[tn][tj * 4 + 3] = p3;
        __syncthreads();
        if (tid < 128) {
            float s = 0.f;
#pragma unroll
            for (int r = 0; r < 8; ++r) s += red[r][tid];
            atomicAdd(&pooled[g * 128 + tid], s);
        }
        __syncthreads();
    }
}

// ================= final FC head (counts via binary search on sorted batch) ======

__device__ __forceinline__ int lower_bound_batch(const int* __restrict__ batch, int val) {
    int lo = 0, hi = N_NODES;
    while (lo < hi) {
        int mid = (lo + hi) >> 1;
        if (batch[mid] < val) lo = mid + 1; else hi = mid;
    }
    return lo;
}

__global__ void k_fc(const float* __restrict__ pooled, const int* __restrict__ batch,
                     const float* __restrict__ Wf1, const float* __restrict__ bf1,
                     const float* __restrict__ Wf2, const float* __restrict__ bf2,
                     float* __restrict__ out) {
    __shared__ float sp[128];
    __shared__ float sh1[64];
    int g = blockIdx.x;
    int t = threadIdx.x;             // 128
    int lo = lower_bound_batch(batch, g);
    int hi = lower_bound_batch(batch, g + 1);
    float inv = 1.0f / fmaxf((float)(hi - lo), 1.0f);
    sp[t] = pooled[g * 128 + t] * inv;
    __syncthreads();
    if (t < 64) {
        float acc = bf1[t];
#pragma unroll 8
        for (int k = 0; k < 128; ++k) acc += sp[k] * Wf1[k * 64 + t];
        sh1[t] = fmaxf(acc, 0.0f);
    }
    __syncthreads();
    if (t < 10) {
        float acc = bf2[t];
#pragma unroll 8
        for (int k = 0; k < 64; ++k) acc += sh1[k] * Wf2[k * 10 + t];
        out[g * 10 + t] = acc;
    }
}

extern "C" void kernel_launch(void* const* d_in, const int* in_sizes, int n_in,
                              void* d_out, int out_size, void* d_ws, size_t ws_size,
                              hipStream_t stream) {
    const float* x     = (const float*)d_in[0];
    const int*   ei    = (const int*)d_in[1];
    const int*   batch = (const int*)d_in[2];
    const float* W1  = (const float*)d_in[3];
    const float* b1  = (const float*)d_in[4];
    const float* W2  = (const float*)d_in[5];
    const float* b2  = (const float*)d_in[6];
    const float* W3  = (const float*)d_in[7];
    const float* b3  = (const float*)d_in[8];
    const float* Wf1 = (const float*)d_in[9];
    const float* bf1 = (const float*)d_in[10];
    const float* Wf2 = (const float*)d_in[11];
    const float* bf2 = (const float*)d_in[12];
    float* out = (float*)d_out;

    const int* src = ei;              // edge_index[0]
    const int* dst = ei + N_EDGES;    // edge_index[1]

    // workspace layout
    float* dinv   = (float*)d_ws;                      // N
    int*   counts = (int*)(dinv + N_NODES);            // N
    int*   row_ptr= counts + N_NODES;                  // N+1
    int*   blksum = row_ptr + N_NODES + 1;             // 256
    int*   cursor = blksum + 256;                      // N
    int*   csr_src= cursor + N_NODES;                  // TOT_E
    float* xs     = (float*)(csr_src + TOT_E);         // N*3
    size_t ofs = (size_t)(xs + (size_t)N_NODES * 3) - (size_t)d_ws;
    ofs = (ofs + 15) & ~(size_t)15;                    // 16B align
    float* bufA   = (float*)((char*)d_ws + ofs);       // N*128 fp32 (agg outputs)
    unsigned short* hb = (unsigned short*)(bufA + (size_t)N_NODES * 128);  // N*128 bf16
    float* pooled = (float*)(hb + (size_t)N_NODES * 128);                  // G*128

    const int TB = 256;

    // ---- zero counts + pooled ----
    hipMemsetAsync(counts, 0, N_NODES * sizeof(int), stream);
    hipMemsetAsync(pooled, 0, N_GRAPHS * 128 * sizeof(float), stream);

    // ---- CSR build + norm + pre-scaled x ----
    k_hist<<<(N_EDGES + TB - 1) / TB, TB, 0, stream>>>(dst, counts);
    k_scan1<<<SCAN_NBLK, SCAN_B, 0, stream>>>(counts, row_ptr, blksum);
    k_scan2<<<1, SCAN_B, 0, stream>>>(blksum);
    k_scan3<<<(N_NODES + TB - 1) / TB, TB, 0, stream>>>(row_ptr, blksum, cursor, counts, dinv, x, xs);
    k_fill<<<(TOT_E + TB - 1) / TB, TB, 0, stream>>>(src, dst, cursor, csr_src);

    // ---- layer 1: agg(xs) @ W1 + b1 -> hb = bf16(dinv*relu) ----
    k_agg3<<<(N_NODES + TB - 1) / TB, TB, 0, stream>>>(xs, row_ptr, csr_src, dinv, bufA);
    k_node_gemm<3, 64, 4><<<(N_NODES + 3) / 4, 64, 0, stream>>>(bufA, W1, b1, dinv, hb);

    // ---- layer 2: agg64(hb) @ W2 + b2 -> hb = bf16(dinv*relu) ----
    k_agg64<<<(N_NODES * 64 + TB - 1) / TB, TB, 0, stream>>>(hb, row_ptr, csr_src, dinv, bufA);
    k_gemm_l2<<<(N_NODES + GM - 1) / GM, 256, 0, stream>>>(bufA, W2, b2, dinv, hb);

    // ---- layer 3: agg128(hb) @ W3 + b3 -> fused relu + mean-pool ----
    k_agg128<<<(N_NODES * 64 + TB - 1) / TB, TB, 0, stream>>>(hb, row_ptr, csr_src, dinv, bufA);
    k_gemm_l3_pool<<<(N_NODES + GM - 1) / GM, 256, 0, stream>>>(bufA, W3, b3, batch, pooled);

    // ---- FC head ----
    k_fc<<<N_GRAPHS, 128, 0, stream>>>(pooled, batch, Wf1, bf1, Wf2, bf2, out);
}

// Round 8
// 342.194 us; speedup vs baseline: 11.0590x; 1.0989x over previous
//
#include <hip/hip_runtime.h>

#define N_NODES 50000
#define N_EDGES 800000
#define N_GRAPHS 64
#define SCAN_B 256
#define SCAN_NBLK ((N_NODES + SCAN_B - 1) / SCAN_B)   // 196

typedef __attribute__((ext_vector_type(8))) short short8;
typedef __attribute__((ext_vector_type(4))) float floatx4;

// fp32 -> bf16 round-to-nearest-even
__device__ __forceinline__ unsigned short f2bf(float f) {
    unsigned int u = __float_as_uint(f);
    u += 0x7FFFu + ((u >> 16) & 1u);
    return (unsigned short)(u >> 16);
}
__device__ __forceinline__ float bf2f(unsigned short h) {
    return __uint_as_float(((unsigned int)h) << 16);
}

// ================= CSR build (real edges only; self-loop handled analytically) ====

__global__ void k_hist(const int* __restrict__ dst, int* counts) {
    int i = blockIdx.x * blockDim.x + threadIdx.x;
    if (i < N_EDGES) atomicAdd(&counts[dst[i]], 1);
}

__global__ void k_scan1(const int* __restrict__ counts, int* row_ptr, int* blksum) {
    __shared__ int s[SCAN_B];
    int i = blockIdx.x * SCAN_B + threadIdx.x;
    int c = (i < N_NODES) ? counts[i] : 0;
    s[threadIdx.x] = c;
    __syncthreads();
    for (int off = 1; off < SCAN_B; off <<= 1) {
        int v = (threadIdx.x >= off) ? s[threadIdx.x - off] : 0;
        __syncthreads();
        s[threadIdx.x] += v;
        __syncthreads();
    }
    if (i < N_NODES) row_ptr[i] = s[threadIdx.x] - c;   // exclusive
    if (threadIdx.x == SCAN_B - 1) blksum[blockIdx.x] = s[SCAN_B - 1];
}

__global__ void k_scan2(int* blksum) {
    __shared__ int s[SCAN_B];
    int t = threadIdx.x;
    int c = (t < SCAN_NBLK) ? blksum[t] : 0;
    s[t] = c;
    __syncthreads();
    for (int off = 1; off < SCAN_B; off <<= 1) {
        int v = (t >= off) ? s[t - off] : 0;
        __syncthreads();
        s[t] += v;
        __syncthreads();
    }
    if (t < SCAN_NBLK) blksum[t] = s[t] - c;            // exclusive
}

// finalize row_ptr, init cursor, dinv = rsqrt(deg = counts+1), xs = x * dinv
__global__ void k_scan3(int* row_ptr, const int* __restrict__ blksum,
                        int* cursor, const int* __restrict__ counts, float* dinv,
                        const float* __restrict__ x, float* __restrict__ xs) {
    int i = blockIdx.x * blockDim.x + threadIdx.x;
    if (i < N_NODES) {
        int v = row_ptr[i] + blksum[i / SCAN_B];
        row_ptr[i] = v;
        cursor[i] = v;
        float di = rsqrtf((float)(counts[i] + 1));
        dinv[i] = di;
        xs[i * 3 + 0] = x[i * 3 + 0] * di;
        xs[i * 3 + 1] = x[i * 3 + 1] * di;
        xs[i * 3 + 2] = x[i * 3 + 2] * di;
    }
    if (i == 0) row_ptr[N_NODES] = N_EDGES;
}

__global__ void k_fill(const int* __restrict__ src, const int* __restrict__ dst,
                       int* cursor, int* csr_src) {
    int e = blockIdx.x * blockDim.x + threadIdx.x;
    if (e >= N_EDGES) return;
    int pos = atomicAdd(&cursor[dst[e]], 1);
    csr_src[pos] = src[e];
}

// ============ weight cast: fp32 [K][128] -> bf16 packed B-frag layout [K/8][128][8]

__global__ void k_wcast(const float* __restrict__ W2, const float* __restrict__ W3,
                        unsigned short* __restrict__ Wb2, unsigned short* __restrict__ Wb3) {
    int i = blockIdx.x * blockDim.x + threadIdx.x;
    if (i < 64 * 128) {
        int k = i >> 7, n = i & 127;
        Wb2[(((k >> 3) * 128) + n) * 8 + (k & 7)] = f2bf(W2[i]);
    } else if (i < 64 * 128 + 128 * 128) {
        int j = i - 64 * 128;
        int k = j >> 7, n = j & 127;
        Wb3[(((k >> 3) * 128) + n) * 8 + (k & 7)] = f2bf(W3[j]);
    }
}

// ================= aggregation: out[d] = dinv[d]*(own + sum_src hs[src]) ==========
// hs pre-scaled by dinv[src]; own term = hs[d] (self-loop).

__global__ void k_agg3(const float* __restrict__ xs, const int* __restrict__ row_ptr,
                       const int* __restrict__ csr_src, const float* __restrict__ dinv,
                       float* __restrict__ out) {
    int n = blockIdx.x * blockDim.x + threadIdx.x;
    if (n >= N_NODES) return;
    int lo = row_ptr[n], hi = row_ptr[n + 1];
    float a0 = xs[n * 3 + 0], a1 = xs[n * 3 + 1], a2 = xs[n * 3 + 2];
    for (int i = lo; i < hi; ++i) {
        int s = csr_src[i];
        a0 += xs[s * 3 + 0];
        a1 += xs[s * 3 + 1];
        a2 += xs[s * 3 + 2];
    }
    float din = dinv[n];
    out[n * 3 + 0] = a0 * din;
    out[n * 3 + 1] = a1 * din;
    out[n * 3 + 2] = a2 * din;
}

// width 64 bf16 in/out: one wave per node, lane = feature
__global__ void k_agg64(const unsigned short* __restrict__ hb, const int* __restrict__ row_ptr,
                        const int* __restrict__ csr_src, const float* __restrict__ dinv,
                        unsigned short* __restrict__ outb) {
    int wv = (blockIdx.x * blockDim.x + threadIdx.x) >> 6;
    int lane = threadIdx.x & 63;
    if (wv >= N_NODES) return;
    int lo = row_ptr[wv], hi = row_ptr[wv + 1];
    float acc = bf2f(hb[(size_t)wv * 64 + lane]);      // self-loop
    for (int base = lo; base < hi; base += 64) {
        int idx = base + lane;
        int sv = csr_src[idx < hi ? idx : hi - 1];
        int cnt = (hi - base < 64) ? (hi - base) : 64;
#pragma unroll 8
        for (int j = 0; j < cnt; ++j) {
            int s = __shfl(sv, j);
            acc += bf2f(hb[(size_t)s * 64 + lane]);
        }
    }
    outb[(size_t)wv * 64 + lane] = f2bf(acc * dinv[wv]);
}

// width 128 bf16 in/out: one wave per node, lane = bf16x2 pair (uint load)
__global__ void k_agg128(const unsigned short* __restrict__ hb, const int* __restrict__ row_ptr,
                         const int* __restrict__ csr_src, const float* __restrict__ dinv,
                         unsigned short* __restrict__ outb) {
    int wv = (blockIdx.x * blockDim.x + threadIdx.x) >> 6;
    int lane = threadIdx.x & 63;
    if (wv >= N_NODES) return;
    int lo = row_ptr[wv], hi = row_ptr[wv + 1];
    const unsigned int* hbu = (const unsigned int*)hb;
    unsigned int uo = hbu[(size_t)wv * 64 + lane];     // self-loop
    float accx = __uint_as_float(uo << 16);
    float accy = __uint_as_float(uo & 0xffff0000u);
    for (int base = lo; base < hi; base += 64) {
        int idx = base + lane;
        int sv = csr_src[idx < hi ? idx : hi - 1];
        int cnt = (hi - base < 64) ? (hi - base) : 64;
#pragma unroll 8
        for (int j = 0; j < cnt; ++j) {
            int s = __shfl(sv, j);
            unsigned int u = hbu[(size_t)s * 64 + lane];
            accx += __uint_as_float(u << 16);
            accy += __uint_as_float(u & 0xffff0000u);
        }
    }
    float din = dinv[wv];
    unsigned int w = (unsigned int)f2bf(accx * din) | ((unsigned int)f2bf(accy * din) << 16);
    ((unsigned int*)outb)[(size_t)wv * 64 + lane] = w;
}

// ================= layer-1 GEMM (K=3) + bias; epilogue bf16(dinv*relu) ==========

template<int IN_W, int OUT_W, int NPB>
__global__ void k_node_gemm(const float* __restrict__ h, const float* __restrict__ W,
                            const float* __restrict__ b, const float* __restrict__ dinv,
                            unsigned short* __restrict__ hb) {
    __shared__ float rows[NPB][IN_W];
    int n0 = blockIdx.x * NPB;
    int j = threadIdx.x;                         // blockDim.x == OUT_W
    for (int t = j; t < NPB * IN_W; t += OUT_W) {
        int m = t / IN_W, k = t - m * IN_W;
        int n = n0 + m;
        rows[m][k] = (n < N_NODES) ? h[(size_t)n * IN_W + k] : 0.0f;
    }
    __syncthreads();
    float acc[NPB];
    float bj = b[j];
#pragma unroll
    for (int m = 0; m < NPB; ++m) acc[m] = bj;
#pragma unroll
    for (int k = 0; k < IN_W; ++k) {
        float wk = W[k * OUT_W + j];
#pragma unroll
        for (int m = 0; m < NPB; ++m) acc[m] += rows[m][k] * wk;
    }
#pragma unroll
    for (int m = 0; m < NPB; ++m) {
        int n = n0 + m;
        if (n < N_NODES)
            hb[(size_t)n * OUT_W + j] = f2bf(fmaxf(acc[m], 0.0f) * dinv[n]);
    }
}

// ================= MFMA GEMM layer 2: [Nx64]bf16 @ [64x128] + b2 -> hb bf16 ======
// 256 thr = 4 waves; block tile 64 rows x 128 cols; wave tile 16 rows x 128 cols.

__global__ __launch_bounds__(256) void k_gemm_l2_mfma(
    const unsigned short* __restrict__ Ab,   // [N][64] bf16
    const unsigned short* __restrict__ Wb,   // packed [8][128][8] bf16
    const float* __restrict__ b,
    const float* __restrict__ dinv,
    unsigned short* __restrict__ hb) {
    __shared__ float sC[64][128];
    int tid = threadIdx.x;
    int wave = tid >> 6, lane = tid & 63;
    int quad = lane >> 4, l16 = lane & 15;
    int n0 = blockIdx.x * 64;
    int arow = n0 + wave * 16 + l16;
    if (arow >= N_NODES) arow = N_NODES - 1;   // clamp; result rows guarded at store

    floatx4 acc[8];
#pragma unroll
    for (int t = 0; t < 8; ++t) acc[t] = (floatx4){0.f, 0.f, 0.f, 0.f};

#pragma unroll
    for (int ks = 0; ks < 2; ++ks) {
        short8 a = *(const short8*)(Ab + (size_t)arow * 64 + ks * 32 + quad * 8);
#pragma unroll
        for (int t = 0; t < 8; ++t) {
            short8 bf = *(const short8*)(Wb + (((ks * 4 + quad) * 128) + t * 16 + l16) * 8);
            acc[t] = __builtin_amdgcn_mfma_f32_16x16x32_bf16(a, bf, acc[t], 0, 0, 0);
        }
    }
    // C/D: col = lane&15 (+16t), row = quad*4 + reg
#pragma unroll
    for (int t = 0; t < 8; ++t)
#pragma unroll
        for (int r = 0; r < 4; ++r)
            sC[wave * 16 + quad * 4 + r][t * 16 + l16] = acc[t][r];
    __syncthreads();
    int tn = tid >> 5, tj = tid & 31;
    float4 bv = *(const float4*)(b + tj * 4);
#pragma unroll
    for (int m = 0; m < 8; ++m) {
        int n = n0 + tn * 8 + m;
        if (n < N_NODES) {
            float di = dinv[n];
            unsigned short h0 = f2bf(fmaxf(sC[tn * 8 + m][tj * 4 + 0] + bv.x, 0.f) * di);
            unsigned short h1 = f2bf(fmaxf(sC[tn * 8 + m][tj * 4 + 1] + bv.y, 0.f) * di);
            unsigned short h2 = f2bf(fmaxf(sC[tn * 8 + m][tj * 4 + 2] + bv.z, 0.f) * di);
            unsigned short h3 = f2bf(fmaxf(sC[tn * 8 + m][tj * 4 + 3] + bv.w, 0.f) * di);
            uint2 w2;
            w2.x = (unsigned int)h0 | ((unsigned int)h1 << 16);
            w2.y = (unsigned int)h2 | ((unsigned int)h3 << 16);
            *(uint2*)(hb + (size_t)n * 128 + tj * 4) = w2;
        }
    }
}

// ======== MFMA GEMM layer 3: [Nx128]bf16 @ [128x128] + b3, relu, fused mean-pool ==

__global__ __launch_bounds__(256) void k_gemm_l3_mfma_pool(
    const unsigned short* __restrict__ Ab,   // [N][128] bf16
    const unsigned short* __restrict__ Wb,   // packed [16][128][8] bf16
    const float* __restrict__ b,
    const int* __restrict__ batch,
    float* __restrict__ pooled) {
    __shared__ float sC[64][128];
    __shared__ float red[8][128];
    __shared__ int sb[64];
    int tid = threadIdx.x;
    int wave = tid >> 6, lane = tid & 63;
    int quad = lane >> 4, l16 = lane & 15;
    int n0 = blockIdx.x * 64;
    int arow = n0 + wave * 16 + l16;
    if (arow >= N_NODES) arow = N_NODES - 1;

    floatx4 acc[8];
#pragma unroll
    for (int t = 0; t < 8; ++t) acc[t] = (floatx4){0.f, 0.f, 0.f, 0.f};

#pragma unroll
    for (int ks = 0; ks < 4; ++ks) {
        short8 a = *(const short8*)(Ab + (size_t)arow * 128 + ks * 32 + quad * 8);
#pragma unroll
        for (int t = 0; t < 8; ++t) {
            short8 bf = *(const short8*)(Wb + (((ks * 4 + quad) * 128) + t * 16 + l16) * 8);
            acc[t] = __builtin_amdgcn_mfma_f32_16x16x32_bf16(a, bf, acc[t], 0, 0, 0);
        }
    }
    // stage relu(acc + bias) into sC
#pragma unroll
    for (int t = 0; t < 8; ++t) {
        float bc = b[t * 16 + l16];
#pragma unroll
        for (int r = 0; r < 4; ++r)
            sC[wave * 16 + quad * 4 + r][t * 16 + l16] = fmaxf(acc[t][r] + bc, 0.f);
    }
    if (tid < 64) {
        int n = n0 + tid;
        sb[tid] = (n < N_NODES) ? batch[n] : -1;
    }
    __syncthreads();
    int g0 = sb[0];
    int last = (n0 + 63 < N_NODES) ? (n0 + 63) : (N_NODES - 1);
    int g1 = batch[last];
    int tn = tid >> 5, tj = tid & 31;
    for (int g = g0; g <= g1; ++g) {
        float p0 = 0.f, p1 = 0.f, p2 = 0.f, p3 = 0.f;
#pragma unroll
        for (int m = 0; m < 8; ++m) {
            if (sb[tn * 8 + m] == g) {
                p0 += sC[tn * 8 + m][tj * 4 + 0];
                p1 += sC[tn * 8 + m][tj * 4 + 1];
                p2 += sC[tn * 8 + m][tj * 4 + 2];
                p3 += sC[tn * 8 + m][tj * 4 + 3];
            }
        }
        red[tn][tj * 4 + 0] = p0;
        red[tn][tj * 4 + 1] = p1;
        red[tn][tj * 4 + 2] = p2;
        red[tn][tj * 4 + 3] = p3;
        __syncthreads();
        if (tid < 128) {
            float s = 0.f;
#pragma unroll
            for (int r = 0; r < 8; ++r) s += red[r][tid];
            atomicAdd(&pooled[g * 128 + tid], s);
        }
        __syncthreads();
    }
}

// ================= final FC head (counts via binary search on sorted batch) ======

__device__ __forceinline__ int lower_bound_batch(const int* __restrict__ batch, int val) {
    int lo = 0, hi = N_NODES;
    while (lo < hi) {
        int mid = (lo + hi) >> 1;
        if (batch[mid] < val) lo = mid + 1; else hi = mid;
    }
    return lo;
}

__global__ void k_fc(const float* __restrict__ pooled, const int* __restrict__ batch,
                     const float* __restrict__ Wf1, const float* __restrict__ bf1,
                     const float* __restrict__ Wf2, const float* __restrict__ bf2,
                     float* __restrict__ out) {
    __shared__ float sp[128];
    __shared__ float sh1[64];
    int g = blockIdx.x;
    int t = threadIdx.x;             // 128
    int lo = lower_bound_batch(batch, g);
    int hi = lower_bound_batch(batch, g + 1);
    float inv = 1.0f / fmaxf((float)(hi - lo), 1.0f);
    sp[t] = pooled[g * 128 + t] * inv;
    __syncthreads();
    if (t < 64) {
        float acc = bf1[t];
#pragma unroll 8
        for (int k = 0; k < 128; ++k) acc += sp[k] * Wf1[k * 64 + t];
        sh1[t] = fmaxf(acc, 0.0f);
    }
    __syncthreads();
    if (t < 10) {
        float acc = bf2[t];
#pragma unroll 8
        for (int k = 0; k < 64; ++k) acc += sh1[k] * Wf2[k * 10 + t];
        out[g * 10 + t] = acc;
    }
}

extern "C" void kernel_launch(void* const* d_in, const int* in_sizes, int n_in,
                              void* d_out, int out_size, void* d_ws, size_t ws_size,
                              hipStream_t stream) {
    const float* x     = (const float*)d_in[0];
    const int*   ei    = (const int*)d_in[1];
    const int*   batch = (const int*)d_in[2];
    const float* W1  = (const float*)d_in[3];
    const float* b1  = (const float*)d_in[4];
    const float* W2  = (const float*)d_in[5];
    const float* b2  = (const float*)d_in[6];
    const float* W3  = (const float*)d_in[7];
    const float* b3  = (const float*)d_in[8];
    const float* Wf1 = (const float*)d_in[9];
    const float* bf1 = (const float*)d_in[10];
    const float* Wf2 = (const float*)d_in[11];
    const float* bf2 = (const float*)d_in[12];
    float* out = (float*)d_out;

    const int* src = ei;              // edge_index[0]
    const int* dst = ei + N_EDGES;    // edge_index[1]

    // workspace layout
    float* dinv   = (float*)d_ws;                      // N
    int*   counts = (int*)(dinv + N_NODES);            // N
    int*   row_ptr= counts + N_NODES;                  // N+1
    int*   blksum = row_ptr + N_NODES + 1;             // 256
    int*   cursor = blksum + 256;                      // N
    int*   csr_src= cursor + N_NODES;                  // N_EDGES
    float* xs     = (float*)(csr_src + N_EDGES);       // N*3
    float* a3     = xs + (size_t)N_NODES * 3;          // N*3 (agg3 out)
    unsigned short* Wb2 = (unsigned short*)(a3 + (size_t)N_NODES * 3);  // 8192
    unsigned short* Wb3 = Wb2 + 64 * 128;                               // 16384
    size_t ofs = (size_t)(Wb3 + 128 * 128) - (size_t)d_ws;
    ofs = (ofs + 15) & ~(size_t)15;
    unsigned short* bufA = (unsigned short*)((char*)d_ws + ofs);        // N*128 bf16 (agg out)
    unsigned short* hb   = bufA + (size_t)N_NODES * 128;                // N*128 bf16 (gemm out)
    float* pooled = (float*)(hb + (size_t)N_NODES * 128);               // G*128

    const int TB = 256;
    const int GEMM_BLKS = (N_NODES + 63) / 64;

    hipMemsetAsync(counts, 0, N_NODES * sizeof(int), stream);
    hipMemsetAsync(pooled, 0, N_GRAPHS * 128 * sizeof(float), stream);

    // ---- CSR build + norm + pre-scaled x + weight cast ----
    k_hist<<<(N_EDGES + TB - 1) / TB, TB, 0, stream>>>(dst, counts);
    k_scan1<<<SCAN_NBLK, SCAN_B, 0, stream>>>(counts, row_ptr, blksum);
    k_scan2<<<1, SCAN_B, 0, stream>>>(blksum);
    k_scan3<<<(N_NODES + TB - 1) / TB, TB, 0, stream>>>(row_ptr, blksum, cursor, counts, dinv, x, xs);
    k_fill<<<(N_EDGES + TB - 1) / TB, TB, 0, stream>>>(src, dst, cursor, csr_src);
    k_wcast<<<(64 * 128 + 128 * 128 + TB - 1) / TB, TB, 0, stream>>>(W2, W3, Wb2, Wb3);

    // ---- layer 1: agg3(xs) @ W1 + b1 -> hb = bf16(dinv*relu) ----
    k_agg3<<<(N_NODES + TB - 1) / TB, TB, 0, stream>>>(xs, row_ptr, csr_src, dinv, a3);
    k_node_gemm<3, 64, 4><<<(N_NODES + 3) / 4, 64, 0, stream>>>(a3, W1, b1, dinv, hb);

    // ---- layer 2: agg64(hb) -> bufA bf16; MFMA @ W2 + b2 -> hb bf16 ----
    k_agg64<<<(N_NODES * 64 + TB - 1) / TB, TB, 0, stream>>>(hb, row_ptr, csr_src, dinv, bufA);
    k_gemm_l2_mfma<<<GEMM_BLKS, 256, 0, stream>>>(bufA, Wb2, b2, dinv, hb);

    // ---- layer 3: agg128(hb) -> bufA bf16; MFMA @ W3 + b3, relu, fused pool ----
    k_agg128<<<(N_NODES * 64 + TB - 1) / TB, TB, 0, stream>>>(hb, row_ptr, csr_src, dinv, bufA);
    k_gemm_l3_mfma_pool<<<GEMM_BLKS, 256, 0, stream>>>(bufA, Wb3, b3, batch, pooled);

    // ---- FC head ----
    k_fc<<<N_GRAPHS, 128, 0, stream>>>(pooled, batch, Wf1, bf1, Wf2, bf2, out);
}